// Round 12
// baseline (131.051 us; speedup 1.0000x reference)
//
#include <hip/hip_runtime.h>

typedef short s16x8 __attribute__((ext_vector_type(8)));
typedef float f32x4 __attribute__((ext_vector_type(4)));
typedef float f32x16 __attribute__((ext_vector_type(16)));
typedef unsigned int u32;
typedef u32 u32x2 __attribute__((ext_vector_type(2)));
typedef u32 u32x4 __attribute__((ext_vector_type(4)));
typedef unsigned short u16;

#define MFMA16(a, b, c) __builtin_amdgcn_mfma_f32_16x16x32_bf16((a), (b), (c), 0, 0, 0)
#define MFMA32(a, b, c) __builtin_amdgcn_mfma_f32_32x32x16_bf16((a), (b), (c), 0, 0, 0)

__device__ __forceinline__ u16 f2bf(float f) {
  unsigned u = __builtin_bit_cast(unsigned, f);
  unsigned r = (u + 0x7FFFu + ((u >> 16) & 1u)) >> 16;
  return (u16)r;
}

__device__ __forceinline__ u32 pack2bf(float lo, float hi) {
  return (u32)f2bf(lo) | ((u32)f2bf(hi) << 16);
}

__device__ __forceinline__ u32 cvtpk(float lo, float hi) {
  u32 r;
  asm("v_cvt_pk_bf16_f32 %0, %1, %2" : "=v"(r) : "v"(lo), "v"(hi));
  return r;
}

__device__ __forceinline__ float bf2f(u32 lo16) {
  return __builtin_bit_cast(float, lo16 << 16);
}

// async global->LDS, 16B per lane. LDS dest must be wave-uniform base (HW adds lane*16).
__device__ __forceinline__ void gl_lds16(const u16* g, u16* s) {
  __builtin_amdgcn_global_load_lds(
      (const __attribute__((address_space(1))) void*)g,
      (__attribute__((address_space(3))) void*)s, 16, 0, 0);
}

// manual 16B global load into VGPRs (counted by hand-written vmcnt only)
__device__ __forceinline__ u32x4 gload16(const u16* p) {
  u32x4 r;
  asm volatile("global_load_dwordx4 %0, %1, off" : "=&v"(r) : "v"(p) : "memory");
  return r;
}

#define VMCNT(n)                                             \
  do {                                                       \
    asm volatile("s_waitcnt vmcnt(" #n ")" ::: "memory");    \
    __builtin_amdgcn_sched_barrier(0);                       \
  } while (0)

// ---------------- fp32 -> bf16 elementwise (x) ----------------
__global__ __launch_bounds__(256) void cvt_bf16(const float* __restrict__ in,
                                                u16* __restrict__ out, int n4) {
  int i = blockIdx.x * 256 + threadIdx.x;
  if (i < n4) {
    float4 v = reinterpret_cast<const float4*>(in)[i];
    ushort4 o;
    o.x = f2bf(v.x); o.y = f2bf(v.y); o.z = f2bf(v.z); o.w = f2bf(v.w);
    reinterpret_cast<ushort4*>(out)[i] = o;
  }
}

// ---------------- all 4 weights: fp32 [1024][1024] -> bf16 transpose (one kernel) ----
__global__ __launch_bounds__(256) void transp4(const float* __restrict__ wq,
                                               const float* __restrict__ wk,
                                               const float* __restrict__ wv,
                                               const float* __restrict__ wo,
                                               u16* __restrict__ wqkvt,
                                               u16* __restrict__ wot, float qscale) {
  __shared__ float tile[64][65];
  int z = blockIdx.z;
  const float* W = (z == 0) ? wq : (z == 1) ? wk : (z == 2) ? wv : wo;
  u16* out = (z < 3) ? (wqkvt + z * 1048576) : wot;
  float sc = (z == 0) ? qscale : 1.0f;
  int n0 = blockIdx.x * 64, k0 = blockIdx.y * 64;
  int t = threadIdx.x;
#pragma unroll
  for (int i = 0; i < 16; i++) {
    int idx = t + i * 256;
    int r = idx >> 6, c = idx & 63;
    tile[r][c] = W[(k0 + r) * 1024 + (n0 + c)];
  }
  __syncthreads();
#pragma unroll
  for (int i = 0; i < 16; i++) {
    int idx = t + i * 256;
    int r = idx >> 6, c = idx & 63;
    out[(n0 + r) * 1024 + (k0 + c)] = f2bf(tile[c][r] * sc);
  }
}

// ---------------- 2-phase global_load_lds GEMM: C = A[M][1024] @ Bt[N][1024]^T ------
// MODE 0: fused QKV epilogue. outp = base of {qb, kb, vtb} (each 4M u16).
//         V^T keys are stored bit2<->bit3 swapped within each 16-block so that
//         attention's P fragments need no cross-lane exchange.
// MODE 1: fp32 out [M][1024] = acc + bias[n]
template <int MODE>
__global__ __launch_bounds__(256) void gemm2(const u16* __restrict__ A,
                                             const u16* __restrict__ Bt,
                                             const float* __restrict__ bias,
                                             void* __restrict__ outp) {
  constexpr int K = 1024, NT = K / 32;
  __shared__ __align__(16) u16 As[2][128 * 32];
  __shared__ __align__(16) u16 Bs[2][128 * 32];
  int t = threadIdx.x, w = t >> 6, l = t & 63;
  int m0 = blockIdx.y * 128, n0 = blockIdx.x * 128;
  int wm = (w >> 1) * 64, wn = (w & 1) * 64;
  int g = l >> 4, ql = l & 15;

  f32x4 acc[4][4];
#pragma unroll
  for (int i = 0; i < 4; i++)
#pragma unroll
    for (int j = 0; j < 4; j++) acc[i][j] = f32x4{0.f, 0.f, 0.f, 0.f};

  int lrow = l >> 2, lcol = (l & 3) * 8;
  const u16* Ag0 = A + (m0 + 32 * w + lrow) * K + lcol;
  const u16* Bg0 = Bt + (n0 + 32 * w + lrow) * K + lcol;
  u16* Asw[2] = {&As[0][(32 * w) * 32], &As[1][(32 * w) * 32]};
  u16* Bsw[2] = {&Bs[0][(32 * w) * 32], &Bs[1][(32 * w) * 32]};

#define STAGE(buf, kt)                              \
  do {                                              \
    int k0_ = (kt) * 32;                            \
    gl_lds16(Ag0 + k0_, Asw[buf]);                  \
    gl_lds16(Ag0 + 16 * K + k0_, Asw[buf] + 512);   \
    gl_lds16(Bg0 + k0_, Bsw[buf]);                  \
    gl_lds16(Bg0 + 16 * K + k0_, Bsw[buf] + 512);   \
  } while (0)

#define COMPUTE(buf)                                                              \
  do {                                                                            \
    s16x8 af[4], bv[4];                                                           \
    _Pragma("unroll") for (int fm = 0; fm < 4; fm++)                              \
        af[fm] = *reinterpret_cast<const s16x8*>(                                 \
            &As[buf][(wm + fm * 16 + ql) * 32 + g * 8]);                          \
    _Pragma("unroll") for (int fn = 0; fn < 4; fn++)                              \
        bv[fn] = *reinterpret_cast<const s16x8*>(                                 \
            &Bs[buf][(wn + fn * 16 + ql) * 32 + g * 8]);                          \
    _Pragma("unroll") for (int fm = 0; fm < 4; fm++)                              \
        _Pragma("unroll") for (int fn = 0; fn < 4; fn++)                          \
            acc[fm][fn] = MFMA16(af[fm], bv[fn], acc[fm][fn]);                    \
  } while (0)

  STAGE(0, 0);
  __syncthreads();
  int cur = 0;
  for (int kt = 0; kt < NT - 1; kt++) {
    STAGE(cur ^ 1, kt + 1);
    COMPUTE(cur);
    __syncthreads();
    cur ^= 1;
  }
  COMPUTE(cur);
#undef STAGE
#undef COMPUTE

#pragma unroll
  for (int fm = 0; fm < 4; fm++)
#pragma unroll
    for (int fn = 0; fn < 4; fn++)
#pragma unroll
      for (int j = 0; j < 4; j++) {
        int m = m0 + wm + fm * 16 + g * 4 + j;
        int n = n0 + wn + fn * 16 + ql;
        float v = acc[fm][fn][j];
        if (MODE == 0) {
          int proj = n >> 10, nn = n & 1023;
          int bh = (m >> 11) * 16 + (nn >> 6);
          int hd = nn & 63, srow = m & 2047;
          u16* o = (u16*)outp + proj * 4194304;
          if (proj < 2) {
            o[(bh * 2048 + srow) * 64 + hd] = f2bf(v);
          } else {
            // key-permuted V^T: swap bits 2<->3 of key index within 16-block
            int sp = (srow & ~12) | ((srow & 4) << 1) | ((srow & 8) >> 1);
            o[(bh * 64 + hd) * 2048 + sp] = f2bf(v);
          }
        } else {
          ((float*)outp)[m * 1024 + n] = v + bias[n];
        }
      }
}

// ---------------- flash attention: 4-wave blocks, K in LDS (6-buf), V direct -------
// Q,K: [BH=32][S=2048][64] bf16 (Q pre-scaled by 0.125*log2e); Vt: [BH][64][2048] bf16
// (key-permuted). 960 blocks x 256 threads. Unit u = B>>5 (LUT below), head =
// (B&7)+8*((B>>3)&3) (XCD-pinned). Band = 128 q rows (wave w owns band*128+w*32..+32).
// Band b has 4(b+1) 32-key tiles; chunks of <=24 tiles; bands 0-5 direct, 6-15 split.
// ALL VMEM is inline asm with hand-counted FIFO vmcnt; 1 s_barrier per 2 tiles.
__global__ __launch_bounds__(256, 3) void attn_kernel(const u16* __restrict__ Q,
                                                      const u16* __restrict__ Kb,
                                                      const u16* __restrict__ Vt,
                                                      u16* __restrict__ Ctx,
                                                      u16* __restrict__ part_o,
                                                      float* __restrict__ part_l) {
  // K: 6 bufs x 2048 u16 (24 KB); epilogue tl overlays (4 x 2176 u16).
  __shared__ __align__(16) u16 shm[12288];
  int tid = threadIdx.x, w = tid >> 6, l = tid & 63;
  int lq = l & 31, h = l >> 5;

  int B = blockIdx.x;
  int head = (B & 7) + 8 * ((B >> 3) & 3);
  int u = B >> 5;  // 0..29, longest chunks first
  const signed char BANDv[30] = {5, 6, 7, 8, 9, 10, 11, 11, 12, 12, 13, 13, 14, 14, 15,
                                 15, 4, 10, 3, 9, 15, 2, 8, 14, 1, 7, 13, 0, 6, 12};
  const signed char CKv[30] = {0, 0, 0, 0, 0, 0, 0, 1, 0, 1, 0, 1, 0, 1, 0,
                               1, 0, 1, 0, 1, 2, 0, 1, 2, 0, 1, 2, 0, 1, 2};
  int band = BANDv[u], ck = CKv[u];
  int t0 = ck * 24;
  int tb = 4 * band + 4;
  int t1 = (tb < t0 + 24) ? tb : (t0 + 24);
  int nbody = (t1 - t0) >> 1;
  int dtile = band * 4 + w;
  int q0w = band * 128 + w * 32;
  int q = q0w + lq;

  const u16* Qp = Q + (head * 2048 + q0w) * 64;
  const u16* Kp = Kb + head * 2048 * 64;
  const u16* Vp = Vt + head * 64 * 2048;

  // K staging source (pre-swizzled slot, rule #21) and LDS lane-linear dest base
  int krow = w * 8 + (l >> 3);
  const u16* kgs = Kp + krow * 64 + (((l & 7) ^ (krow & 7)) * 8);
  int kldso = w * 512;

  // V fragment base addresses (per-lane): vaddr[dt*2+kh] + kb
  const u16* vaddr[4];
#pragma unroll
  for (int dt = 0; dt < 2; dt++)
#pragma unroll
    for (int kh = 0; kh < 2; kh++)
      vaddr[dt * 2 + kh] = Vp + (dt * 32 + lq) * 2048 + kh * 16 + h * 8;

#define STAGEK(idx, tile) gl_lds16(kgs + (tile)*2048, shm + (idx)*2048 + kldso)

  // ---- prologue: qf(4 asm) ; K t0..t0+3 (4 lds) ; V(t0)->VA, V(t0+1)->VB (8 asm)
  u32x4 qfr[4];
#pragma unroll
  for (int f = 0; f < 4; f++) qfr[f] = gload16(Qp + lq * 64 + f * 16 + h * 8);
  STAGEK(0, t0);
  STAGEK(1, t0 + 1);
  STAGEK(2, t0 + 2);
  STAGEK(3, t0 + 3);
  u32x4 VA[4], VB[4];
#pragma unroll
  for (int x = 0; x < 4; x++) VA[x] = gload16(vaddr[x] + t0 * 32);
#pragma unroll
  for (int x = 0; x < 4; x++) VB[x] = gload16(vaddr[x] + t0 * 32 + 32);
  VMCNT(10);  // qf + K(t0) + K(t0+1) landed; K(t0+2..3) + VA + VB in flight
  __builtin_amdgcn_s_barrier();
  __builtin_amdgcn_sched_barrier(0);

  s16x8 qf[4];
#pragma unroll
  for (int f = 0; f < 4; f++) qf[f] = __builtin_bit_cast(s16x8, qfr[f]);

  f32x16 oacc[2];
#pragma unroll
  for (int dt = 0; dt < 2; dt++)
#pragma unroll
    for (int rr = 0; rr < 16; rr++) oacc[dt][rr] = 0.f;
  float lsum = 0.f;

#define TILE_COMPUTE(KT, BUFI, VREG, MIDWAIT)                                     \
  do {                                                                            \
    int kt_ = (KT);                                                               \
    if (kt_ <= dtile) {                                                           \
      const u16* kb_ = shm + (BUFI)*2048;                                         \
      s16x8 kc[4];                                                                \
      _Pragma("unroll") for (int f = 0; f < 4; f++)                               \
          kc[f] = *reinterpret_cast<const s16x8*>(                                \
              &kb_[lq * 64 + (((f * 2 + h) ^ (lq & 7)) * 8)]);                    \
      f32x16 s;                                                                   \
      _Pragma("unroll") for (int rr = 0; rr < 16; rr++) s[rr] = 0.f;              \
      __builtin_amdgcn_s_setprio(1);                                              \
      _Pragma("unroll") for (int f = 0; f < 4; f++) s = MFMA32(kc[f], qf[f], s);  \
      __builtin_amdgcn_s_setprio(0);                                              \
      float p[16];                                                                \
      if (kt_ == dtile) {                                                         \
        int kb0_ = kt_ * 32;                                                      \
        _Pragma("unroll") for (int rr = 0; rr < 16; rr++) {                       \
          int key = kb0_ + (rr & 3) + 8 * (rr >> 2) + 4 * h;                      \
          float e = exp2f(s[rr]);                                                 \
          p[rr] = (key <= q) ? e : 0.f;                                           \
        }                                                                         \
      } else {                                                                    \
        _Pragma("unroll") for (int rr = 0; rr < 16; rr++) p[rr] = exp2f(s[rr]);   \
      }                                                                           \
      _Pragma("unroll") for (int rr = 0; rr < 16; rr++) lsum += p[rr];            \
      u32 pw[2][4];                                                               \
      _Pragma("unroll") for (int kh = 0; kh < 2; kh++)                            \
          _Pragma("unroll") for (int uu = 0; uu < 4; uu++)                        \
              pw[kh][uu] = cvtpk(p[kh * 8 + 2 * uu], p[kh * 8 + 2 * uu + 1]);     \
      MIDWAIT;                                                                    \
      __builtin_amdgcn_s_setprio(1);                                              \
      _Pragma("unroll") for (int kh = 0; kh < 2; kh++) {                          \
        s16x8 pf = __builtin_bit_cast(                                            \
            s16x8, u32x4{pw[kh][0], pw[kh][1], pw[kh][2], pw[kh][3]});            \
        oacc[0] = MFMA32(__builtin_bit_cast(s16x8, VREG[0 * 2 + kh]), pf, oacc[0]); \
        oacc[1] = MFMA32(__builtin_bit_cast(s16x8, VREG[1 * 2 + kh]), pf, oacc[1]); \
      }                                                                           \
      __builtin_amdgcn_s_setprio(0);                                              \
    }                                                                             \
  } while (0)

  int bi = 0;
  for (int j = 0; j < nbody; j++) {
    int kt = t0 + 2 * j;

    TILE_COMPUTE(kt, bi, VA, VMCNT(4));      // VA landed; VB + next Ks in flight
    TILE_COMPUTE(kt + 1, bi + 1, VB, VMCNT(0));  // only VB outstanding here

    // body end: stage K(kt+4..5), issue V(kt+2..3); certify prev Ks; barrier
    bool moreV = (kt + 2 < t1);
    bool moreK = (kt + 4 < t1);
    int s0 = (bi >= 2) ? (bi - 2) : (bi + 4);
    if (moreK) {
      STAGEK(s0, kt + 4);
      STAGEK(s0 + 1, kt + 5);
    }
    if (moreV) {
#pragma unroll
      for (int x = 0; x < 4; x++) VA[x] = gload16(vaddr[x] + (kt + 2) * 32);
#pragma unroll
      for (int x = 0; x < 4; x++) VB[x] = gload16(vaddr[x] + (kt + 3) * 32);
      VMCNT(10);
    } else {
      VMCNT(0);
    }
    __builtin_amdgcn_s_barrier();
    __builtin_amdgcn_sched_barrier(0);
    bi += 2;
    if (bi >= 6) bi -= 6;
  }
#undef TILE_COMPUTE
#undef STAGEK

  if (band >= 6) {
    // partial record: rec = head*24 + base(band) + ck
    int base = (band <= 11) ? (band - 6) * 2 : 12 + (band - 12) * 3;
    int rec = head * 24 + base + ck;
    u32* po = reinterpret_cast<u32*>(part_o) + (size_t)rec * 4096 + w * 1024 + l * 16;
#pragma unroll
    for (int dt = 0; dt < 2; dt++)
#pragma unroll
      for (int i = 0; i < 8; i++)
        po[dt * 8 + i] = pack2bf(oacc[dt][2 * i], oacc[dt][2 * i + 1]);
    part_l[(size_t)rec * 256 + w * 64 + l] = lsum;
    return;
  }

  // direct path: normalize, transpose O^T[d][q] -> [q][d] through LDS (overlay), store
  float ltot = lsum + __shfl_xor(lsum, 32);
  float invl = 1.0f / ltot;
  u16* myl = shm + w * 2176;
#pragma unroll
  for (int dt = 0; dt < 2; dt++)
#pragma unroll
    for (int i = 0; i < 8; i++) {
      int d = ((2 * i) & 3) + 8 * (i >> 1) + 4 * h + dt * 32;
      u32 pkv = pack2bf(oacc[dt][2 * i] * invl, oacc[dt][2 * i + 1] * invl);
      *reinterpret_cast<u32*>(myl + lq * 68 + d) = pkv;
    }

  int b = head >> 4, hh = head & 15;
  int gbase = b * 2048 + q0w;
#pragma unroll
  for (int i = 0; i < 8; i++) {
    int chunkk = i * 64 + l;
    int row = chunkk >> 4, col4 = (chunkk & 15) * 4;
    u32x2 v = *reinterpret_cast<const u32x2*>(myl + row * 68 + col4);
    *reinterpret_cast<u32x2*>(Ctx + (gbase + row) * 1024 + hh * 64 + col4) = v;
  }
}

// ---------------- combine 2-3 partials per (head, band 6-15, wave) -> Ctx ----------
// 320 blocks x 256 threads; wave wv handles unit blockIdx*4+wv of 1280.
__global__ __launch_bounds__(256) void attn_combine(const u16* __restrict__ part_o,
                                                    const float* __restrict__ part_l,
                                                    u16* __restrict__ Ctx) {
  __shared__ __align__(16) u16 tl[4][32 * 68];
  int wv = threadIdx.x >> 6, l = threadIdx.x & 63;
  int lq = l & 31, h = l >> 5;
  int unit = blockIdx.x * 4 + wv;  // 1280 = 32 heads x 10 bands x 4 waves
  int head = unit & 31, rest = unit >> 5;
  int band = 6 + (rest >> 2), w = rest & 3;
  int nc = (band <= 11) ? 2 : 3;
  int base = (band <= 11) ? (band - 6) * 2 : 12 + (band - 12) * 3;
  int rec0 = head * 24 + base;

  float lsum = 0.f;
  float of[32];
#pragma unroll
  for (int i = 0; i < 32; i++) of[i] = 0.f;
  for (int cc = 0; cc < nc; cc++) {
    int rec = rec0 + cc;
    lsum += part_l[(size_t)rec * 256 + w * 64 + l];
    const u32* po =
        reinterpret_cast<const u32*>(part_o) + (size_t)rec * 4096 + w * 1024 + l * 16;
#pragma unroll
    for (int uu = 0; uu < 16; uu++) {
      u32 a = po[uu];
      of[2 * uu] += bf2f(a & 0xFFFFu);
      of[2 * uu + 1] += bf2f(a >> 16);
    }
  }

  float ltot = lsum + __shfl_xor(lsum, 32);
  float invl = 1.0f / ltot;

  u16* myl = tl[wv];
#pragma unroll
  for (int dt = 0; dt < 2; dt++)
#pragma unroll
    for (int i = 0; i < 8; i++) {
      int uu = dt * 8 + i;
      int d = ((2 * i) & 3) + 8 * (i >> 1) + 4 * h + dt * 32;
      *reinterpret_cast<u32*>(myl + lq * 68 + d) =
          pack2bf(of[2 * uu] * invl, of[2 * uu + 1] * invl);
    }

  int b_ = head >> 4, hh = head & 15;
  int gbase = b_ * 2048 + band * 128 + w * 32;
#pragma unroll
  for (int i = 0; i < 8; i++) {
    int chunkk = i * 64 + l;
    int row = chunkk >> 4, col4 = (chunkk & 15) * 4;
    u32x2 v = *reinterpret_cast<const u32x2*>(myl + row * 68 + col4);
    *reinterpret_cast<u32x2*>(Ctx + (gbase + row) * 1024 + hh * 64 + col4) = v;
  }
}

extern "C" void kernel_launch(void* const* d_in, const int* in_sizes, int n_in,
                              void* d_out, int out_size, void* d_ws, size_t ws_size,
                              hipStream_t stream) {
  const float* x = (const float*)d_in[0];
  const float* wq = (const float*)d_in[1];
  const float* wk = (const float*)d_in[2];
  const float* wv = (const float*)d_in[3];
  const float* wo = (const float*)d_in[4];
  const float* bo = (const float*)d_in[5];

  char* ws = (char*)d_ws;
  const size_t MB = 1 << 20;
  u16* xb    = (u16*)(ws + 0 * MB);    // 8 MB : x bf16 (dead after QKV GEMM)
  u16* wqkvt = (u16*)(ws + 8 * MB);    // 6 MB : [wq^T;wk^T;wv^T] (dead after QKV GEMM)
  u16* wot   = (u16*)(ws + 14 * MB);   // 2 MB : wo^T (live until final GEMM)
  u16* qkv   = (u16*)(ws + 16 * MB);   // 24 MB: qb @16, kb @24, vtb @32
  u16* ctx   = (u16*)(ws + 40 * MB);   // 8 MB : ctx [4096][1024]
  // attention partials alias the dead xb/wqkvt region (12.75 MB < 14 MB):
  u16* part_o   = (u16*)(ws + 0 * MB);      // 12 MB : 768 records x 16 KB
  float* part_l = (float*)(ws + 12582912);  // 768 KB : 768 records x 256 floats

  const float QSCALE = 0.125f * 1.44269504f;  // 1/sqrt(64) * log2(e)

  cvt_bf16<<<4096, 256, 0, stream>>>(x, xb, 1048576);
  transp4<<<dim3(16, 16, 4), 256, 0, stream>>>(wq, wk, wv, wo, wqkvt, wot, QSCALE);

  gemm2<0><<<dim3(24, 32), 256, 0, stream>>>(xb, wqkvt, nullptr, qkv);

  attn_kernel<<<960, 256, 0, stream>>>(qkv, qkv + 4194304, qkv + 8388608, ctx,
                                       part_o, part_l);
  attn_combine<<<320, 256, 0, stream>>>(part_o, part_l, ctx);

  gemm2<1><<<dim3(8, 32), 256, 0, stream>>>(ctx, wot, bo, d_out);
}

// Round 13
// 124.364 us; speedup vs baseline: 1.0538x; 1.0538x over previous
//
#include <hip/hip_runtime.h>

typedef short s16x8 __attribute__((ext_vector_type(8)));
typedef float f32x4 __attribute__((ext_vector_type(4)));
typedef float f32x16 __attribute__((ext_vector_type(16)));
typedef unsigned int u32;
typedef u32 u32x2 __attribute__((ext_vector_type(2)));
typedef u32 u32x4 __attribute__((ext_vector_type(4)));
typedef unsigned short u16;

#define MFMA16(a, b, c) __builtin_amdgcn_mfma_f32_16x16x32_bf16((a), (b), (c), 0, 0, 0)
#define MFMA32(a, b, c) __builtin_amdgcn_mfma_f32_32x32x16_bf16((a), (b), (c), 0, 0, 0)

__device__ __forceinline__ u16 f2bf(float f) {
  unsigned u = __builtin_bit_cast(unsigned, f);
  unsigned r = (u + 0x7FFFu + ((u >> 16) & 1u)) >> 16;
  return (u16)r;
}

__device__ __forceinline__ u32 pack2bf(float lo, float hi) {
  return (u32)f2bf(lo) | ((u32)f2bf(hi) << 16);
}

__device__ __forceinline__ u32 cvtpk(float lo, float hi) {
  u32 r;
  asm("v_cvt_pk_bf16_f32 %0, %1, %2" : "=v"(r) : "v"(lo), "v"(hi));
  return r;
}

__device__ __forceinline__ float bf2f(u32 lo16) {
  return __builtin_bit_cast(float, lo16 << 16);
}

// async global->LDS, 16B per lane. LDS dest must be wave-uniform base (HW adds lane*16).
__device__ __forceinline__ void gl_lds16(const u16* g, u16* s) {
  __builtin_amdgcn_global_load_lds(
      (const __attribute__((address_space(1))) void*)g,
      (__attribute__((address_space(3))) void*)s, 16, 0, 0);
}

#define VMCNT(n)                                             \
  do {                                                       \
    asm volatile("s_waitcnt vmcnt(" #n ")" ::: "memory");    \
    __builtin_amdgcn_sched_barrier(0);                       \
  } while (0)

#define LGKM0                                                \
  do {                                                       \
    asm volatile("s_waitcnt lgkmcnt(0)" ::: "memory");       \
    __builtin_amdgcn_sched_barrier(0);                       \
  } while (0)

// ---------------- fp32 -> bf16 elementwise (x) ----------------
__global__ __launch_bounds__(256) void cvt_bf16(const float* __restrict__ in,
                                                u16* __restrict__ out, int n4) {
  int i = blockIdx.x * 256 + threadIdx.x;
  if (i < n4) {
    float4 v = reinterpret_cast<const float4*>(in)[i];
    ushort4 o;
    o.x = f2bf(v.x); o.y = f2bf(v.y); o.z = f2bf(v.z); o.w = f2bf(v.w);
    reinterpret_cast<ushort4*>(out)[i] = o;
  }
}

// ---------------- all 4 weights: fp32 [1024][1024] -> bf16 transpose (one kernel) ----
__global__ __launch_bounds__(256) void transp4(const float* __restrict__ wq,
                                               const float* __restrict__ wk,
                                               const float* __restrict__ wv,
                                               const float* __restrict__ wo,
                                               u16* __restrict__ wqkvt,
                                               u16* __restrict__ wot, float qscale) {
  __shared__ float tile[64][65];
  int z = blockIdx.z;
  const float* W = (z == 0) ? wq : (z == 1) ? wk : (z == 2) ? wv : wo;
  u16* out = (z < 3) ? (wqkvt + z * 1048576) : wot;
  float sc = (z == 0) ? qscale : 1.0f;
  int n0 = blockIdx.x * 64, k0 = blockIdx.y * 64;
  int t = threadIdx.x;
#pragma unroll
  for (int i = 0; i < 16; i++) {
    int idx = t + i * 256;
    int r = idx >> 6, c = idx & 63;
    tile[r][c] = W[(k0 + r) * 1024 + (n0 + c)];
  }
  __syncthreads();
#pragma unroll
  for (int i = 0; i < 16; i++) {
    int idx = t + i * 256;
    int r = idx >> 6, c = idx & 63;
    out[(n0 + r) * 1024 + (k0 + c)] = f2bf(tile[c][r] * sc);
  }
}

// ---------------- 8-wave 256x128 QKV GEMM, 3-K-step LDS ring, counted vmcnt --------
// C[4096][3072] = A[4096][1024] @ Bt[3072][1024]^T, fused QKV epilogue (as gemm2 MODE0).
// BK=32; ring slot r=s%3 computed while step s+2 staged into slot (s+2)%3 (freed s-1).
// LDS/slot: A 256x32 (8192 u16) + B 128x32 (4096 u16) = 12288 u16; x3 = 72KB.
// Swizzle: logical 16B-slot g stored at physical g^(row&3); staged via pre-swizzled
// global source col (rule #21). Per step: 2 phases x 8 MFMA; vmcnt(3) + 1 s_barrier.
__global__ __launch_bounds__(512, 4) void gemm8(const u16* __restrict__ A,
                                                const u16* __restrict__ Bt,
                                                void* __restrict__ outp) {
  __shared__ __align__(16) u16 shm[36864];
  int t = threadIdx.x, w = t >> 6, l = t & 63;
  int ql = l & 15, g = l >> 4;
  int m0 = blockIdx.y * 256, n0 = blockIdx.x * 128;
  int wm64 = (w >> 1) * 64;  // 4 M sub-bands
  int wn64 = (w & 1) * 64;   // 2 N sub-bands
  int xs = ((g ^ (l & 3)) * 8);  // swizzled 16B slot offset (row&3 == ql&3)

  // staging source (pre-swizzled col) : lane covers row r0 = w*16 + l>>2, phys slot l&3
  int r0 = w * 16 + (l >> 2);
  int c0 = (l & 3) ^ (r0 & 3);
  const u16* pA0 = A + (m0 + r0) * 1024 + c0 * 8;      // A half 0 (rows 0-127)
  const u16* pB0 = Bt + (n0 + r0) * 1024 + c0 * 8;     // B (rows 0-127)
  int w512 = w * 512;

  f32x4 acc[4][4];
#pragma unroll
  for (int i = 0; i < 4; i++)
#pragma unroll
    for (int j = 0; j < 4; j++) acc[i][j] = f32x4{0.f, 0.f, 0.f, 0.f};

#define STAGE_A(slot, s)                                        \
  do {                                                          \
    u16* d_ = shm + (slot)*12288 + w512;                        \
    gl_lds16(pA0 + (s)*32, d_);                                 \
    gl_lds16(pA0 + 131072 + (s)*32, d_ + 4096);                 \
  } while (0)
#define STAGE_B(slot, s) gl_lds16(pB0 + (s)*32, shm + (slot)*12288 + 8192 + w512)

  // prologue: stage steps 0,1 ; certify step 0 ; barrier
  STAGE_A(0, 0);
  STAGE_B(0, 0);
  STAGE_A(1, 1);
  STAGE_B(1, 1);
  VMCNT(3);
  __builtin_amdgcn_s_barrier();
  __builtin_amdgcn_sched_barrier(0);

  int r = 0;
  for (int s = 0; s < 32; ++s) {
    const u16* As_ = shm + r * 12288;
    const u16* Bs_ = As_ + 8192;
    int r2 = r - 1;
    if (r2 < 0) r2 = 2;
    bool st = (s < 30);

    // ---- phase 0: A-frags fm0,1 + all B-frags; stage A halves of s+2
    s16x8 af0 = *reinterpret_cast<const s16x8*>(As_ + (wm64 + 0 + ql) * 32 + xs);
    s16x8 af1 = *reinterpret_cast<const s16x8*>(As_ + (wm64 + 16 + ql) * 32 + xs);
    s16x8 bv[4];
#pragma unroll
    for (int fn = 0; fn < 4; fn++)
      bv[fn] = *reinterpret_cast<const s16x8*>(Bs_ + (wn64 + fn * 16 + ql) * 32 + xs);
    if (st) STAGE_A(r2, s + 2);
    LGKM0;
    __builtin_amdgcn_s_setprio(1);
#pragma unroll
    for (int fn = 0; fn < 4; fn++) acc[0][fn] = MFMA16(af0, bv[fn], acc[0][fn]);
#pragma unroll
    for (int fn = 0; fn < 4; fn++) acc[1][fn] = MFMA16(af1, bv[fn], acc[1][fn]);
    __builtin_amdgcn_s_setprio(0);

    // ---- phase 1: A-frags fm2,3; stage B of s+2
    s16x8 af2 = *reinterpret_cast<const s16x8*>(As_ + (wm64 + 32 + ql) * 32 + xs);
    s16x8 af3 = *reinterpret_cast<const s16x8*>(As_ + (wm64 + 48 + ql) * 32 + xs);
    if (st) STAGE_B(r2, s + 2);
    LGKM0;
    __builtin_amdgcn_s_setprio(1);
#pragma unroll
    for (int fn = 0; fn < 4; fn++) acc[2][fn] = MFMA16(af2, bv[fn], acc[2][fn]);
#pragma unroll
    for (int fn = 0; fn < 4; fn++) acc[3][fn] = MFMA16(af3, bv[fn], acc[3][fn]);
    __builtin_amdgcn_s_setprio(0);

    // ---- boundary: counted wait (certify step s+1), single barrier
    if (st) {
      VMCNT(3);
    } else if (s == 30) {
      VMCNT(0);
    }
    if (s < 31) {
      __builtin_amdgcn_s_barrier();
      __builtin_amdgcn_sched_barrier(0);
    }
    r = (r == 2) ? 0 : r + 1;
  }
#undef STAGE_A
#undef STAGE_B

  // fused QKV epilogue (identical semantics to gemm2 MODE 0)
#pragma unroll
  for (int fm = 0; fm < 4; fm++)
#pragma unroll
    for (int fn = 0; fn < 4; fn++)
#pragma unroll
      for (int j = 0; j < 4; j++) {
        int m = m0 + wm64 + fm * 16 + g * 4 + j;
        int n = n0 + wn64 + fn * 16 + ql;
        float v = acc[fm][fn][j];
        int proj = n >> 10, nn = n & 1023;
        int bh = (m >> 11) * 16 + (nn >> 6);
        int hd = nn & 63, srow = m & 2047;
        u16* o = (u16*)outp + proj * 4194304;
        if (proj < 2) {
          o[(bh * 2048 + srow) * 64 + hd] = f2bf(v);
        } else {
          // key-permuted V^T: swap bits 2<->3 of key index within 16-block
          int sp = (srow & ~12) | ((srow & 4) << 1) | ((srow & 8) >> 1);
          o[(bh * 64 + hd) * 2048 + sp] = f2bf(v);
        }
      }
}

// ---------------- 2-phase global_load_lds GEMM (proj): fp32 out = A@Bt^T + bias -----
__global__ __launch_bounds__(256) void gemm2(const u16* __restrict__ A,
                                             const u16* __restrict__ Bt,
                                             const float* __restrict__ bias,
                                             float* __restrict__ outp) {
  constexpr int K = 1024, NT = K / 32;
  __shared__ __align__(16) u16 As[2][128 * 32];
  __shared__ __align__(16) u16 Bs[2][128 * 32];
  int t = threadIdx.x, w = t >> 6, l = t & 63;
  int m0 = blockIdx.y * 128, n0 = blockIdx.x * 128;
  int wm = (w >> 1) * 64, wn = (w & 1) * 64;
  int g = l >> 4, ql = l & 15;

  f32x4 acc[4][4];
#pragma unroll
  for (int i = 0; i < 4; i++)
#pragma unroll
    for (int j = 0; j < 4; j++) acc[i][j] = f32x4{0.f, 0.f, 0.f, 0.f};

  int lrow = l >> 2, lcol = (l & 3) * 8;
  const u16* Ag0 = A + (m0 + 32 * w + lrow) * K + lcol;
  const u16* Bg0 = Bt + (n0 + 32 * w + lrow) * K + lcol;
  u16* Asw[2] = {&As[0][(32 * w) * 32], &As[1][(32 * w) * 32]};
  u16* Bsw[2] = {&Bs[0][(32 * w) * 32], &Bs[1][(32 * w) * 32]};

#define STAGE(buf, kt)                              \
  do {                                              \
    int k0_ = (kt) * 32;                            \
    gl_lds16(Ag0 + k0_, Asw[buf]);                  \
    gl_lds16(Ag0 + 16 * K + k0_, Asw[buf] + 512);   \
    gl_lds16(Bg0 + k0_, Bsw[buf]);                  \
    gl_lds16(Bg0 + 16 * K + k0_, Bsw[buf] + 512);   \
  } while (0)

#define COMPUTE(buf)                                                              \
  do {                                                                            \
    s16x8 af[4], bv[4];                                                           \
    _Pragma("unroll") for (int fm = 0; fm < 4; fm++)                              \
        af[fm] = *reinterpret_cast<const s16x8*>(                                 \
            &As[buf][(wm + fm * 16 + ql) * 32 + g * 8]);                          \
    _Pragma("unroll") for (int fn = 0; fn < 4; fn++)                              \
        bv[fn] = *reinterpret_cast<const s16x8*>(                                 \
            &Bs[buf][(wn + fn * 16 + ql) * 32 + g * 8]);                          \
    _Pragma("unroll") for (int fm = 0; fm < 4; fm++)                              \
        _Pragma("unroll") for (int fn = 0; fn < 4; fn++)                          \
            acc[fm][fn] = MFMA16(af[fm], bv[fn], acc[fm][fn]);                    \
  } while (0)

  STAGE(0, 0);
  __syncthreads();
  int cur = 0;
  for (int kt = 0; kt < NT - 1; kt++) {
    STAGE(cur ^ 1, kt + 1);
    COMPUTE(cur);
    __syncthreads();
    cur ^= 1;
  }
  COMPUTE(cur);
#undef STAGE
#undef COMPUTE

#pragma unroll
  for (int fm = 0; fm < 4; fm++)
#pragma unroll
    for (int fn = 0; fn < 4; fn++)
#pragma unroll
      for (int j = 0; j < 4; j++) {
        int m = m0 + wm + fm * 16 + g * 4 + j;
        int n = n0 + wn + fn * 16 + ql;
        outp[m * 1024 + n] = acc[fm][fn][j] + bias[n];
      }
}

// ---------------- flash attention: 8-wave blocks, shared K/V in LDS (R10) ----------
__global__ __launch_bounds__(512, 4) void attn_kernel(const u16* __restrict__ Q,
                                                      const u16* __restrict__ Kb,
                                                      const u16* __restrict__ Vt,
                                                      u16* __restrict__ Ctx,
                                                      u16* __restrict__ part_o,
                                                      float* __restrict__ part_l) {
  __shared__ __align__(16) u16 Kl[2][2048];
  __shared__ __align__(16) u16 Vl[2][2048];
  __shared__ __align__(16) u16 tl[8][32 * 68];
  int tid = threadIdx.x, w = tid >> 6, l = tid & 63;
  int lq = l & 31, h = l >> 5;

  int B = blockIdx.x;
  int head = (B & 7) + 8 * ((B >> 3) & 3);  // head % 8 == B % 8 -> XCD-pinned
  int u = B >> 5;                           // 0..15, longest chunks first
  const signed char QCv[16] = {3, 2, 4, 4, 6, 6, 6, 7, 7, 7, 7, 5, 5, 5, 1, 0};
  const signed char CKv[16] = {0, 0, 0, 1, 0, 1, 2, 0, 1, 2, 3, 0, 1, 2, 0, 0};
  int qc = QCv[u], ck = CKv[u];
  int t0, t1;
  if (qc == 4)      { t0 = ck * 20; t1 = t0 + 20; }
  else if (qc == 5) { t0 = ck * 16; t1 = t0 + 16; }
  else if (qc == 6) { t0 = (ck == 0) ? 0 : (ck == 1) ? 19 : 38;
                      t1 = (ck == 0) ? 19 : (ck == 1) ? 38 : 56; }
  else if (qc == 7) { t0 = ck * 16; t1 = t0 + 16; }
  else              { t0 = 0; t1 = (qc + 1) * 8; }
  int dtile = qc * 8 + w;
  int q0w = qc * 256 + w * 32;
  int q = q0w + lq;

  const u16* Qp = Q + (head * 2048 + q0w) * 64;
  const u16* Kp = Kb + head * 2048 * 64;
  const u16* Vp = Vt + head * 64 * 2048;

  s16x8 qf[4];
#pragma unroll
  for (int f = 0; f < 4; f++)
    qf[f] = *reinterpret_cast<const s16x8*>(Qp + lq * 64 + f * 16 + h * 8);

  const u16* gstage;
  int gstep, ldsoff;
  if (w < 4) {
    int row = w * 8 + (l >> 3);
    int c = (l & 7) ^ (row & 7);
    gstage = Kp + row * 64 + c * 8;
    gstep = 32 * 64;
    ldsoff = w * 512;
  } else {
    int lin = (w - 4) * 64 + l;
    int rp = lin >> 3, pos = lin & 7;
    int d = rp * 2 + (pos >> 2);
    int c = (pos & 3) ^ (rp & 3);
    gstage = Vp + d * 2048 + c * 8;
    gstep = 32;
    ldsoff = (w - 4) * 512;
  }

  f32x16 oacc[2];
#pragma unroll
  for (int dt = 0; dt < 2; dt++)
#pragma unroll
    for (int rr = 0; rr < 16; rr++) oacc[dt][rr] = 0.f;
  float lsum = 0.f;

#define STAGEKV(buf, kt)                                                  \
  gl_lds16(gstage + (kt) * gstep, ((w < 4) ? Kl[buf] : Vl[buf]) + ldsoff)

  STAGEKV(0, t0);
  __syncthreads();
  int cur = 0;

  for (int kt = t0; kt < t1; kt++) {
    if (kt + 1 < t1) STAGEKV(cur ^ 1, kt + 1);

    if (kt <= dtile) {
      s16x8 kc[4];
#pragma unroll
      for (int f = 0; f < 4; f++)
        kc[f] = *reinterpret_cast<const s16x8*>(
            &Kl[cur][lq * 64 + (((f * 2 + h) ^ (lq & 7)) * 8)]);

      f32x16 s;
#pragma unroll
      for (int rr = 0; rr < 16; rr++) s[rr] = 0.f;
      __builtin_amdgcn_s_setprio(1);
#pragma unroll
      for (int f = 0; f < 4; f++) s = MFMA32(kc[f], qf[f], s);
      __builtin_amdgcn_s_setprio(0);

      float p[16];
      if (kt == dtile) {
        int kb = kt * 32;
#pragma unroll
        for (int rr = 0; rr < 16; rr++) {
          int key = kb + (rr & 3) + 8 * (rr >> 2) + 4 * h;
          float e = exp2f(s[rr]);
          p[rr] = (key <= q) ? e : 0.f;
        }
      } else {
#pragma unroll
        for (int rr = 0; rr < 16; rr++) p[rr] = exp2f(s[rr]);
      }
#pragma unroll
      for (int rr = 0; rr < 16; rr++) lsum += p[rr];

      u32 pw[2][4];
#pragma unroll
      for (int kh = 0; kh < 2; kh++)
#pragma unroll
        for (int uu = 0; uu < 4; uu++)
          pw[kh][uu] = cvtpk(p[kh * 8 + 2 * uu], p[kh * 8 + 2 * uu + 1]);

      s16x8 vf[2][2];
#pragma unroll
      for (int dt = 0; dt < 2; dt++)
#pragma unroll
        for (int kh = 0; kh < 2; kh++) {
          int rp = dt * 16 + (lq >> 1);
          int soff = rp * 64 + (lq & 1) * 32 + (((kh * 2 + h) ^ (rp & 3)) * 8);
          vf[dt][kh] = *reinterpret_cast<const s16x8*>(&Vl[cur][soff]);
        }

      __builtin_amdgcn_s_setprio(1);
#pragma unroll
      for (int kh = 0; kh < 2; kh++) {
        s16x8 pf = __builtin_bit_cast(
            s16x8, u32x4{pw[kh][0], pw[kh][1], pw[kh][2], pw[kh][3]});
        oacc[0] = MFMA32(vf[0][kh], pf, oacc[0]);
        oacc[1] = MFMA32(vf[1][kh], pf, oacc[1]);
      }
      __builtin_amdgcn_s_setprio(0);
    }

    __syncthreads();
    cur ^= 1;
  }
#undef STAGEKV

  if (qc >= 4) {
    int base = (qc == 4) ? 0 : (qc == 5) ? 2 : (qc == 6) ? 5 : 8;
    int rec = head * 12 + base + ck;
    u32* po = reinterpret_cast<u32*>(part_o) + (size_t)rec * 8192 + w * 1024 + l * 16;
#pragma unroll
    for (int dt = 0; dt < 2; dt++)
#pragma unroll
      for (int i = 0; i < 8; i++)
        po[dt * 8 + i] = pack2bf(oacc[dt][2 * i], oacc[dt][2 * i + 1]);
    part_l[(size_t)rec * 512 + w * 64 + l] = lsum;
    return;
  }

  float ltot = lsum + __shfl_xor(lsum, 32);
  float invl = 1.0f / ltot;
  u16* myl = tl[w];
#pragma unroll
  for (int dt = 0; dt < 2; dt++)
#pragma unroll
    for (int i = 0; i < 8; i++) {
      int d = ((2 * i) & 3) + 8 * (i >> 1) + 4 * h + dt * 32;
      u32 pkv = pack2bf(oacc[dt][2 * i] * invl, oacc[dt][2 * i + 1] * invl);
      *reinterpret_cast<u32*>(myl + lq * 68 + d) = pkv;
    }

  int b = head >> 4, hh = head & 15;
  int gbase = b * 2048 + q0w;
#pragma unroll
  for (int i = 0; i < 8; i++) {
    int chunkk = i * 64 + l;
    int row = chunkk >> 4, col4 = (chunkk & 15) * 4;
    u32x2 v = *reinterpret_cast<const u32x2*>(myl + row * 68 + col4);
    *reinterpret_cast<u32x2*>(Ctx + (gbase + row) * 1024 + hh * 64 + col4) = v;
  }
}

// ---------------- combine 2-4 partials per (head, qc>=4, wave q-tile) -> Ctx --------
__global__ __launch_bounds__(256) void attn_combine(const u16* __restrict__ part_o,
                                                    const float* __restrict__ part_l,
                                                    u16* __restrict__ Ctx) {
  __shared__ __align__(16) u16 tl[4][32 * 68];
  int wv = threadIdx.x >> 6, l = threadIdx.x & 63;
  int lq = l & 31, h = l >> 5;
  int unit = blockIdx.x * 4 + wv;
  int head = unit & 31, rest = unit >> 5;
  int qc = 4 + (rest >> 3), w = rest & 7;
  int nc = (qc == 4) ? 2 : (qc == 7) ? 4 : 3;
  int base = (qc == 4) ? 0 : (qc == 5) ? 2 : (qc == 6) ? 5 : 8;
  int rec0 = head * 12 + base;

  float lsum = 0.f;
  float of[32];
#pragma unroll
  for (int i = 0; i < 32; i++) of[i] = 0.f;
  for (int cc = 0; cc < nc; cc++) {
    int rec = rec0 + cc;
    lsum += part_l[(size_t)rec * 512 + w * 64 + l];
    const u32* po =
        reinterpret_cast<const u32*>(part_o) + (size_t)rec * 8192 + w * 1024 + l * 16;
#pragma unroll
    for (int uu = 0; uu < 16; uu++) {
      u32 a = po[uu];
      of[2 * uu] += bf2f(a & 0xFFFFu);
      of[2 * uu + 1] += bf2f(a >> 16);
    }
  }

  float ltot = lsum + __shfl_xor(lsum, 32);
  float invl = 1.0f / ltot;

  u16* myl = tl[wv];
#pragma unroll
  for (int dt = 0; dt < 2; dt++)
#pragma unroll
    for (int i = 0; i < 8; i++) {
      int uu = dt * 8 + i;
      int d = ((2 * i) & 3) + 8 * (i >> 1) + 4 * h + dt * 32;
      *reinterpret_cast<u32*>(myl + lq * 68 + d) =
          pack2bf(of[2 * uu] * invl, of[2 * uu + 1] * invl);
    }

  int b_ = head >> 4, hh = head & 15;
  int gbase = b_ * 2048 + qc * 256 + w * 32;
#pragma unroll
  for (int i = 0; i < 8; i++) {
    int chunkk = i * 64 + l;
    int row = chunkk >> 4, col4 = (chunkk & 15) * 4;
    u32x2 v = *reinterpret_cast<const u32x2*>(myl + row * 68 + col4);
    *reinterpret_cast<u32x2*>(Ctx + (gbase + row) * 1024 + hh * 64 + col4) = v;
  }
}

extern "C" void kernel_launch(void* const* d_in, const int* in_sizes, int n_in,
                              void* d_out, int out_size, void* d_ws, size_t ws_size,
                              hipStream_t stream) {
  const float* x = (const float*)d_in[0];
  const float* wq = (const float*)d_in[1];
  const float* wk = (const float*)d_in[2];
  const float* wv = (const float*)d_in[3];
  const float* wo = (const float*)d_in[4];
  const float* bo = (const float*)d_in[5];

  char* ws = (char*)d_ws;
  const size_t MB = 1 << 20;
  u16* xb    = (u16*)(ws + 0 * MB);    // 8 MB : x bf16 (dead after QKV GEMM)
  u16* wqkvt = (u16*)(ws + 8 * MB);    // 6 MB : [wq^T;wk^T;wv^T] (dead after QKV GEMM)
  u16* wot   = (u16*)(ws + 14 * MB);   // 2 MB : wo^T (live until final GEMM)
  u16* qkv   = (u16*)(ws + 16 * MB);   // 24 MB: qb @16, kb @24, vtb @32
  u16* ctx   = (u16*)(ws + 40 * MB);   // 8 MB : ctx [4096][1024]
  // attention partials alias the dead xb/wqkvt region (13.4 MB < 14 MB):
  u16* part_o   = (u16*)(ws + 0 * MB);        // 12 MB : 384 records x 32 KB
  float* part_l = (float*)(ws + 12582912);    // 0.75 MB: 384 records x 512 floats

  const float QSCALE = 0.125f * 1.44269504f;  // 1/sqrt(64) * log2(e)

  cvt_bf16<<<4096, 256, 0, stream>>>(x, xb, 1048576);
  transp4<<<dim3(16, 16, 4), 256, 0, stream>>>(wq, wk, wv, wo, wqkvt, wot, QSCALE);

  gemm8<<<dim3(24, 16), 512, 0, stream>>>(xb, wqkvt, qkv);

  attn_kernel<<<512, 512, 0, stream>>>(qkv, qkv + 4194304, qkv + 8388608, ctx,
                                       part_o, part_l);
  attn_combine<<<256, 256, 0, stream>>>(part_o, part_l, ctx);

  gemm2<<<dim3(8, 32), 256, 0, stream>>>(ctx, wot, bo, (float*)d_out);
}

// Round 14
// 122.021 us; speedup vs baseline: 1.0740x; 1.0192x over previous
//
#include <hip/hip_runtime.h>

typedef short s16x8 __attribute__((ext_vector_type(8)));
typedef float f32x4 __attribute__((ext_vector_type(4)));
typedef float f32x16 __attribute__((ext_vector_type(16)));
typedef unsigned int u32;
typedef u32 u32x2 __attribute__((ext_vector_type(2)));
typedef u32 u32x4 __attribute__((ext_vector_type(4)));
typedef unsigned short u16;

#define MFMA16(a, b, c) __builtin_amdgcn_mfma_f32_16x16x32_bf16((a), (b), (c), 0, 0, 0)
#define MFMA32(a, b, c) __builtin_amdgcn_mfma_f32_32x32x16_bf16((a), (b), (c), 0, 0, 0)

__device__ __forceinline__ u16 f2bf(float f) {
  unsigned u = __builtin_bit_cast(unsigned, f);
  unsigned r = (u + 0x7FFFu + ((u >> 16) & 1u)) >> 16;
  return (u16)r;
}

__device__ __forceinline__ u32 pack2bf(float lo, float hi) {
  return (u32)f2bf(lo) | ((u32)f2bf(hi) << 16);
}

__device__ __forceinline__ u32 cvtpk(float lo, float hi) {
  u32 r;
  asm("v_cvt_pk_bf16_f32 %0, %1, %2" : "=v"(r) : "v"(lo), "v"(hi));
  return r;
}

__device__ __forceinline__ float bf2f(u32 lo16) {
  return __builtin_bit_cast(float, lo16 << 16);
}

// async global->LDS, 16B per lane. LDS dest must be wave-uniform base (HW adds lane*16).
__device__ __forceinline__ void gl_lds16(const u16* g, u16* s) {
  __builtin_amdgcn_global_load_lds(
      (const __attribute__((address_space(1))) void*)g,
      (__attribute__((address_space(3))) void*)s, 16, 0, 0);
}

// ---------------- fp32 -> bf16 elementwise (x) ----------------
__global__ __launch_bounds__(256) void cvt_bf16(const float* __restrict__ in,
                                                u16* __restrict__ out, int n4) {
  int i = blockIdx.x * 256 + threadIdx.x;
  if (i < n4) {
    float4 v = reinterpret_cast<const float4*>(in)[i];
    ushort4 o;
    o.x = f2bf(v.x); o.y = f2bf(v.y); o.z = f2bf(v.z); o.w = f2bf(v.w);
    reinterpret_cast<ushort4*>(out)[i] = o;
  }
}

// ---------------- all 4 weights: fp32 [1024][1024] -> bf16 transpose (one kernel) ----
__global__ __launch_bounds__(256) void transp4(const float* __restrict__ wq,
                                               const float* __restrict__ wk,
                                               const float* __restrict__ wv,
                                               const float* __restrict__ wo,
                                               u16* __restrict__ wqkvt,
                                               u16* __restrict__ wot, float qscale) {
  __shared__ float tile[64][65];
  int z = blockIdx.z;
  const float* W = (z == 0) ? wq : (z == 1) ? wk : (z == 2) ? wv : wo;
  u16* out = (z < 3) ? (wqkvt + z * 1048576) : wot;
  float sc = (z == 0) ? qscale : 1.0f;
  int n0 = blockIdx.x * 64, k0 = blockIdx.y * 64;
  int t = threadIdx.x;
#pragma unroll
  for (int i = 0; i < 16; i++) {
    int idx = t + i * 256;
    int r = idx >> 6, c = idx & 63;
    tile[r][c] = W[(k0 + r) * 1024 + (n0 + c)];
  }
  __syncthreads();
#pragma unroll
  for (int i = 0; i < 16; i++) {
    int idx = t + i * 256;
    int r = idx >> 6, c = idx & 63;
    out[(n0 + r) * 1024 + (k0 + c)] = f2bf(tile[c][r] * sc);
  }
}

// ---------------- 2-phase global_load_lds GEMM: C = A[M][1024] @ Bt[N][1024]^T ------
// LDS swizzle: physical 16B slot = logical g ^ ((row>>1)&3); staged via pre-swizzled
// global source col (both-sides rule). Fragment reads are 2-way (free) instead of 4-8x.
// MODE 0: fused QKV, LDS-bounce coalesced epilogue:
//   proj 0/1 (Q,K): out bf16 [bh][2048][64], 128B-contiguous u32x2 runs.
//   proj 2   (V)  : out bf16 [bh][64][2048] key-permuted (bits 2<->3 in 16-blocks),
//                   transposed through the bounce tile, 32B runs.
// MODE 1: fp32 out [M][1024] = acc + bias[n] (direct coalesced stores)
template <int MODE>
__global__ __launch_bounds__(256) void gemm2(const u16* __restrict__ A,
                                             const u16* __restrict__ Bt,
                                             const float* __restrict__ bias,
                                             void* __restrict__ outp) {
  constexpr int K = 1024, NT = K / 32;
  __shared__ __align__(16) u16 As[2][128 * 32];
  __shared__ __align__(16) u16 Bs[2][128 * 32];
  int t = threadIdx.x, w = t >> 6, l = t & 63;
  int m0 = blockIdx.y * 128, n0 = blockIdx.x * 128;
  int wm = (w >> 1) * 64, wn = (w & 1) * 64;
  int g = l >> 4, ql = l & 15;
  int xs = (g ^ ((ql >> 1) & 3)) * 8;  // swizzled fragment chunk (per-thread const)

  f32x4 acc[4][4];
#pragma unroll
  for (int i = 0; i < 4; i++)
#pragma unroll
    for (int j = 0; j < 4; j++) acc[i][j] = f32x4{0.f, 0.f, 0.f, 0.f};

  // staging: lane covers rows 32w + (l>>2) (+16 for second half), phys chunk l&3;
  // pre-swizzled source col = (l&3) ^ ((row>>1)&3) = (l&3) ^ ((l>>3)&3)
  int lrow = l >> 2, lcol = ((l & 3) ^ ((l >> 3) & 3)) * 8;
  const u16* Ag0 = A + (m0 + 32 * w + lrow) * K + lcol;
  const u16* Bg0 = Bt + (n0 + 32 * w + lrow) * K + lcol;
  u16* Asw[2] = {&As[0][(32 * w) * 32], &As[1][(32 * w) * 32]};
  u16* Bsw[2] = {&Bs[0][(32 * w) * 32], &Bs[1][(32 * w) * 32]};

#define STAGE(buf, kt)                              \
  do {                                              \
    int k0_ = (kt) * 32;                            \
    gl_lds16(Ag0 + k0_, Asw[buf]);                  \
    gl_lds16(Ag0 + 16 * K + k0_, Asw[buf] + 512);   \
    gl_lds16(Bg0 + k0_, Bsw[buf]);                  \
    gl_lds16(Bg0 + 16 * K + k0_, Bsw[buf] + 512);   \
  } while (0)

#define COMPUTE(buf)                                                              \
  do {                                                                            \
    s16x8 af[4], bv[4];                                                           \
    _Pragma("unroll") for (int fm = 0; fm < 4; fm++)                              \
        af[fm] = *reinterpret_cast<const s16x8*>(                                 \
            &As[buf][(wm + fm * 16 + ql) * 32 + xs]);                             \
    _Pragma("unroll") for (int fn = 0; fn < 4; fn++)                              \
        bv[fn] = *reinterpret_cast<const s16x8*>(                                 \
            &Bs[buf][(wn + fn * 16 + ql) * 32 + xs]);                             \
    _Pragma("unroll") for (int fm = 0; fm < 4; fm++)                              \
        _Pragma("unroll") for (int fn = 0; fn < 4; fn++)                          \
            acc[fm][fn] = MFMA16(af[fm], bv[fn], acc[fm][fn]);                    \
  } while (0)

  STAGE(0, 0);
  __syncthreads();
  int cur = 0;
  for (int kt = 0; kt < NT - 1; kt++) {
    STAGE(cur ^ 1, kt + 1);
    COMPUTE(cur);
    __syncthreads();
    cur ^= 1;
  }
  COMPUTE(cur);
#undef STAGE
#undef COMPUTE

  if (MODE == 1) {
#pragma unroll
    for (int fm = 0; fm < 4; fm++)
#pragma unroll
      for (int fn = 0; fn < 4; fn++)
#pragma unroll
        for (int j = 0; j < 4; j++) {
          int m = m0 + wm + fm * 16 + g * 4 + j;
          int n = n0 + wn + fn * 16 + ql;
          ((float*)outp)[m * 1024 + n] = acc[fm][fn][j] + bias[n];
        }
    return;
  }

  // MODE 0: LDS-bounce epilogue. Per-wave 16x68 tile in As (dead after loop).
  __syncthreads();
  u16* tlw = &As[0][0] + w * 2048;
  int nb = n0 + wn;              // 64-aligned; whole wave band in one projection
  int proj = nb >> 10;
  int nn6 = (nb & 1023) >> 6;    // head-within-projection

  if (proj < 2) {
    u16* o = (u16*)outp + proj * 4194304;
#pragma unroll
    for (int fm = 0; fm < 4; fm++) {
#pragma unroll
      for (int fn = 0; fn < 4; fn++)
#pragma unroll
        for (int j = 0; j < 4; j++)
          tlw[(g * 4 + j) * 68 + fn * 16 + ql] = f2bf(acc[fm][fn][j]);
#pragma unroll
      for (int i = 0; i < 4; i++) {
        int row = i * 4 + g;
        u32x2 v = *reinterpret_cast<const u32x2*>(tlw + row * 68 + ql * 4);
        int m = m0 + wm + fm * 16 + row;
        int bh = (m >> 11) * 16 + nn6;
        *reinterpret_cast<u32x2*>(o + (bh * 2048 + (m & 2047)) * 64 + ql * 4) = v;
      }
    }
  } else {
    u16* o = (u16*)outp + 8388608;
    int kq = (l & 3) * 4;
    int pr = ((kq & 4) << 1) | ((kq & 8) >> 1);  // permuted base row (bits 2<->3)
#pragma unroll
    for (int fm = 0; fm < 4; fm++) {
#pragma unroll
      for (int fn = 0; fn < 4; fn++)
#pragma unroll
        for (int j = 0; j < 4; j++)
          tlw[(g * 4 + j) * 68 + fn * 16 + ql] = f2bf(acc[fm][fn][j]);
      int m = m0 + wm + fm * 16;
      int batch = m >> 11, key0 = m & 2047;
      int bh = batch * 16 + nn6;
#pragma unroll
      for (int i = 0; i < 4; i++) {
        int hd = i * 16 + (l >> 2);
        u16 v0 = tlw[(pr + 0) * 68 + hd];
        u16 v1 = tlw[(pr + 1) * 68 + hd];
        u16 v2 = tlw[(pr + 2) * 68 + hd];
        u16 v3 = tlw[(pr + 3) * 68 + hd];
        u32x2 v;
        v[0] = (u32)v0 | ((u32)v1 << 16);
        v[1] = (u32)v2 | ((u32)v3 << 16);
        *reinterpret_cast<u32x2*>(o + (bh * 64 + hd) * 2048 + key0 + kq) = v;
      }
    }
  }
}

// ---------------- flash attention: 8-wave blocks, shared K/V in LDS (R10) ----------
__global__ __launch_bounds__(512, 4) void attn_kernel(const u16* __restrict__ Q,
                                                      const u16* __restrict__ Kb,
                                                      const u16* __restrict__ Vt,
                                                      u16* __restrict__ Ctx,
                                                      u16* __restrict__ part_o,
                                                      float* __restrict__ part_l) {
  __shared__ __align__(16) u16 Kl[2][2048];
  __shared__ __align__(16) u16 Vl[2][2048];
  __shared__ __align__(16) u16 tl[8][32 * 68];
  int tid = threadIdx.x, w = tid >> 6, l = tid & 63;
  int lq = l & 31, h = l >> 5;

  int B = blockIdx.x;
  int head = (B & 7) + 8 * ((B >> 3) & 3);  // head % 8 == B % 8 -> XCD-pinned
  int u = B >> 5;                           // 0..15, longest chunks first
  const signed char QCv[16] = {3, 2, 4, 4, 6, 6, 6, 7, 7, 7, 7, 5, 5, 5, 1, 0};
  const signed char CKv[16] = {0, 0, 0, 1, 0, 1, 2, 0, 1, 2, 3, 0, 1, 2, 0, 0};
  int qc = QCv[u], ck = CKv[u];
  int t0, t1;
  if (qc == 4)      { t0 = ck * 20; t1 = t0 + 20; }
  else if (qc == 5) { t0 = ck * 16; t1 = t0 + 16; }
  else if (qc == 6) { t0 = (ck == 0) ? 0 : (ck == 1) ? 19 : 38;
                      t1 = (ck == 0) ? 19 : (ck == 1) ? 38 : 56; }
  else if (qc == 7) { t0 = ck * 16; t1 = t0 + 16; }
  else              { t0 = 0; t1 = (qc + 1) * 8; }
  int dtile = qc * 8 + w;
  int q0w = qc * 256 + w * 32;
  int q = q0w + lq;

  const u16* Qp = Q + (head * 2048 + q0w) * 64;
  const u16* Kp = Kb + head * 2048 * 64;
  const u16* Vp = Vt + head * 64 * 2048;

  s16x8 qf[4];
#pragma unroll
  for (int f = 0; f < 4; f++)
    qf[f] = *reinterpret_cast<const s16x8*>(Qp + lq * 64 + f * 16 + h * 8);

  const u16* gstage;
  int gstep, ldsoff;
  if (w < 4) {
    int row = w * 8 + (l >> 3);
    int c = (l & 7) ^ (row & 7);
    gstage = Kp + row * 64 + c * 8;
    gstep = 32 * 64;
    ldsoff = w * 512;
  } else {
    int lin = (w - 4) * 64 + l;
    int rp = lin >> 3, pos = lin & 7;
    int d = rp * 2 + (pos >> 2);
    int c = (pos & 3) ^ (rp & 3);
    gstage = Vp + d * 2048 + c * 8;
    gstep = 32;
    ldsoff = (w - 4) * 512;
  }

  f32x16 oacc[2];
#pragma unroll
  for (int dt = 0; dt < 2; dt++)
#pragma unroll
    for (int rr = 0; rr < 16; rr++) oacc[dt][rr] = 0.f;
  float lsum = 0.f;

#define STAGEKV(buf, kt)                                                  \
  gl_lds16(gstage + (kt) * gstep, ((w < 4) ? Kl[buf] : Vl[buf]) + ldsoff)

  STAGEKV(0, t0);
  __syncthreads();
  int cur = 0;

  for (int kt = t0; kt < t1; kt++) {
    if (kt + 1 < t1) STAGEKV(cur ^ 1, kt + 1);

    if (kt <= dtile) {
      s16x8 kc[4];
#pragma unroll
      for (int f = 0; f < 4; f++)
        kc[f] = *reinterpret_cast<const s16x8*>(
            &Kl[cur][lq * 64 + (((f * 2 + h) ^ (lq & 7)) * 8)]);

      f32x16 s;
#pragma unroll
      for (int rr = 0; rr < 16; rr++) s[rr] = 0.f;
      __builtin_amdgcn_s_setprio(1);
#pragma unroll
      for (int f = 0; f < 4; f++) s = MFMA32(kc[f], qf[f], s);
      __builtin_amdgcn_s_setprio(0);

      float p[16];
      if (kt == dtile) {
        int kb = kt * 32;
#pragma unroll
        for (int rr = 0; rr < 16; rr++) {
          int key = kb + (rr & 3) + 8 * (rr >> 2) + 4 * h;
          float e = exp2f(s[rr]);
          p[rr] = (key <= q) ? e : 0.f;
        }
      } else {
#pragma unroll
        for (int rr = 0; rr < 16; rr++) p[rr] = exp2f(s[rr]);
      }
#pragma unroll
      for (int rr = 0; rr < 16; rr++) lsum += p[rr];

      u32 pw[2][4];
#pragma unroll
      for (int kh = 0; kh < 2; kh++)
#pragma unroll
        for (int uu = 0; uu < 4; uu++)
          pw[kh][uu] = cvtpk(p[kh * 8 + 2 * uu], p[kh * 8 + 2 * uu + 1]);

      s16x8 vf[2][2];
#pragma unroll
      for (int dt = 0; dt < 2; dt++)
#pragma unroll
        for (int kh = 0; kh < 2; kh++) {
          int rp = dt * 16 + (lq >> 1);
          int soff = rp * 64 + (lq & 1) * 32 + (((kh * 2 + h) ^ (rp & 3)) * 8);
          vf[dt][kh] = *reinterpret_cast<const s16x8*>(&Vl[cur][soff]);
        }

      __builtin_amdgcn_s_setprio(1);
#pragma unroll
      for (int kh = 0; kh < 2; kh++) {
        s16x8 pf = __builtin_bit_cast(
            s16x8, u32x4{pw[kh][0], pw[kh][1], pw[kh][2], pw[kh][3]});
        oacc[0] = MFMA32(vf[0][kh], pf, oacc[0]);
        oacc[1] = MFMA32(vf[1][kh], pf, oacc[1]);
      }
      __builtin_amdgcn_s_setprio(0);
    }

    __syncthreads();
    cur ^= 1;
  }
#undef STAGEKV

  if (qc >= 4) {
    int base = (qc == 4) ? 0 : (qc == 5) ? 2 : (qc == 6) ? 5 : 8;
    int rec = head * 12 + base + ck;
    u32* po = reinterpret_cast<u32*>(part_o) + (size_t)rec * 8192 + w * 1024 + l * 16;
#pragma unroll
    for (int dt = 0; dt < 2; dt++)
#pragma unroll
      for (int i = 0; i < 8; i++)
        po[dt * 8 + i] = pack2bf(oacc[dt][2 * i], oacc[dt][2 * i + 1]);
    part_l[(size_t)rec * 512 + w * 64 + l] = lsum;
    return;
  }

  float ltot = lsum + __shfl_xor(lsum, 32);
  float invl = 1.0f / ltot;
  u16* myl = tl[w];
#pragma unroll
  for (int dt = 0; dt < 2; dt++)
#pragma unroll
    for (int i = 0; i < 8; i++) {
      int d = ((2 * i) & 3) + 8 * (i >> 1) + 4 * h + dt * 32;
      u32 pkv = pack2bf(oacc[dt][2 * i] * invl, oacc[dt][2 * i + 1] * invl);
      *reinterpret_cast<u32*>(myl + lq * 68 + d) = pkv;
    }

  int b = head >> 4, hh = head & 15;
  int gbase = b * 2048 + q0w;
#pragma unroll
  for (int i = 0; i < 8; i++) {
    int chunkk = i * 64 + l;
    int row = chunkk >> 4, col4 = (chunkk & 15) * 4;
    u32x2 v = *reinterpret_cast<const u32x2*>(myl + row * 68 + col4);
    *reinterpret_cast<u32x2*>(Ctx + (gbase + row) * 1024 + hh * 64 + col4) = v;
  }
}

// ---------------- combine 2-4 partials per (head, qc>=4, wave q-tile) -> Ctx --------
__global__ __launch_bounds__(256) void attn_combine(const u16* __restrict__ part_o,
                                                    const float* __restrict__ part_l,
                                                    u16* __restrict__ Ctx) {
  __shared__ __align__(16) u16 tl[4][32 * 68];
  int wv = threadIdx.x >> 6, l = threadIdx.x & 63;
  int lq = l & 31, h = l >> 5;
  int unit = blockIdx.x * 4 + wv;
  int head = unit & 31, rest = unit >> 5;
  int qc = 4 + (rest >> 3), w = rest & 7;
  int nc = (qc == 4) ? 2 : (qc == 7) ? 4 : 3;
  int base = (qc == 4) ? 0 : (qc == 5) ? 2 : (qc == 6) ? 5 : 8;
  int rec0 = head * 12 + base;

  float lsum = 0.f;
  float of[32];
#pragma unroll
  for (int i = 0; i < 32; i++) of[i] = 0.f;
  for (int cc = 0; cc < nc; cc++) {
    int rec = rec0 + cc;
    lsum += part_l[(size_t)rec * 512 + w * 64 + l];
    const u32* po =
        reinterpret_cast<const u32*>(part_o) + (size_t)rec * 8192 + w * 1024 + l * 16;
#pragma unroll
    for (int uu = 0; uu < 16; uu++) {
      u32 a = po[uu];
      of[2 * uu] += bf2f(a & 0xFFFFu);
      of[2 * uu + 1] += bf2f(a >> 16);
    }
  }

  float ltot = lsum + __shfl_xor(lsum, 32);
  float invl = 1.0f / ltot;

  u16* myl = tl[wv];
#pragma unroll
  for (int dt = 0; dt < 2; dt++)
#pragma unroll
    for (int i = 0; i < 8; i++) {
      int uu = dt * 8 + i;
      int d = ((2 * i) & 3) + 8 * (i >> 1) + 4 * h + dt * 32;
      *reinterpret_cast<u32*>(myl + lq * 68 + d) =
          pack2bf(of[2 * uu] * invl, of[2 * uu + 1] * invl);
    }

  int b_ = head >> 4, hh = head & 15;
  int gbase = b_ * 2048 + qc * 256 + w * 32;
#pragma unroll
  for (int i = 0; i < 8; i++) {
    int chunkk = i * 64 + l;
    int row = chunkk >> 4, col4 = (chunkk & 15) * 4;
    u32x2 v = *reinterpret_cast<const u32x2*>(myl + row * 68 + col4);
    *reinterpret_cast<u32x2*>(Ctx + (gbase + row) * 1024 + hh * 64 + col4) = v;
  }
}

extern "C" void kernel_launch(void* const* d_in, const int* in_sizes, int n_in,
                              void* d_out, int out_size, void* d_ws, size_t ws_size,
                              hipStream_t stream) {
  const float* x = (const float*)d_in[0];
  const float* wq = (const float*)d_in[1];
  const float* wk = (const float*)d_in[2];
  const float* wv = (const float*)d_in[3];
  const float* wo = (const float*)d_in[4];
  const float* bo = (const float*)d_in[5];

  char* ws = (char*)d_ws;
  const size_t MB = 1 << 20;
  u16* xb    = (u16*)(ws + 0 * MB);    // 8 MB : x bf16 (dead after QKV GEMM)
  u16* wqkvt = (u16*)(ws + 8 * MB);    // 6 MB : [wq^T;wk^T;wv^T] (dead after QKV GEMM)
  u16* wot   = (u16*)(ws + 14 * MB);   // 2 MB : wo^T (live until final GEMM)
  u16* qkv   = (u16*)(ws + 16 * MB);   // 24 MB: Q @16, K @24, V^T @32
  u16* ctx   = (u16*)(ws + 40 * MB);   // 8 MB : ctx [4096][1024]
  // attention partials alias the dead xb/wqkvt region (13.4 MB < 14 MB):
  u16* part_o   = (u16*)(ws + 0 * MB);        // 12 MB : 384 records x 32 KB
  float* part_l = (float*)(ws + 12582912);    // 0.75 MB: 384 records x 512 floats

  const float QSCALE = 0.125f * 1.44269504f;  // 1/sqrt(64) * log2(e)

  cvt_bf16<<<4096, 256, 0, stream>>>(x, xb, 1048576);
  transp4<<<dim3(16, 16, 4), 256, 0, stream>>>(wq, wk, wv, wo, wqkvt, wot, QSCALE);

  gemm2<0><<<dim3(24, 32), 256, 0, stream>>>(xb, wqkvt, nullptr, qkv);

  attn_kernel<<<512, 512, 0, stream>>>(qkv, qkv + 4194304, qkv + 8388608, ctx,
                                       part_o, part_l);
  attn_combine<<<256, 256, 0, stream>>>(part_o, part_l, ctx);

  gemm2<1><<<dim3(8, 32), 256, 0, stream>>>(ctx, wot, bo, d_out);
}

// Round 15
// 117.615 us; speedup vs baseline: 1.1142x; 1.0375x over previous
//
#include <hip/hip_runtime.h>

typedef short s16x8 __attribute__((ext_vector_type(8)));
typedef float f32x4 __attribute__((ext_vector_type(4)));
typedef float f32x16 __attribute__((ext_vector_type(16)));
typedef unsigned int u32;
typedef u32 u32x2 __attribute__((ext_vector_type(2)));
typedef u32 u32x4 __attribute__((ext_vector_type(4)));
typedef unsigned short u16;

#define MFMA16(a, b, c) __builtin_amdgcn_mfma_f32_16x16x32_bf16((a), (b), (c), 0, 0, 0)
#define MFMA32(a, b, c) __builtin_amdgcn_mfma_f32_32x32x16_bf16((a), (b), (c), 0, 0, 0)

__device__ __forceinline__ u16 f2bf(float f) {
  unsigned u = __builtin_bit_cast(unsigned, f);
  unsigned r = (u + 0x7FFFu + ((u >> 16) & 1u)) >> 16;
  return (u16)r;
}

__device__ __forceinline__ u32 pack2bf(float lo, float hi) {
  return (u32)f2bf(lo) | ((u32)f2bf(hi) << 16);
}

__device__ __forceinline__ u32 cvtpk(float lo, float hi) {
  u32 r;
  asm("v_cvt_pk_bf16_f32 %0, %1, %2" : "=v"(r) : "v"(lo), "v"(hi));
  return r;
}

__device__ __forceinline__ float bf2f(u32 lo16) {
  return __builtin_bit_cast(float, lo16 << 16);
}

// async global->LDS, 16B per lane. LDS dest must be wave-uniform base (HW adds lane*16).
__device__ __forceinline__ void gl_lds16(const u16* g, u16* s) {
  __builtin_amdgcn_global_load_lds(
      (const __attribute__((address_space(1))) void*)g,
      (__attribute__((address_space(3))) void*)s, 16, 0, 0);
}

// ---------------- fp32 -> bf16 elementwise (x) ----------------
__global__ __launch_bounds__(256) void cvt_bf16(const float* __restrict__ in,
                                                u16* __restrict__ out, int n4) {
  int i = blockIdx.x * 256 + threadIdx.x;
  if (i < n4) {
    float4 v = reinterpret_cast<const float4*>(in)[i];
    ushort4 o;
    o.x = f2bf(v.x); o.y = f2bf(v.y); o.z = f2bf(v.z); o.w = f2bf(v.w);
    reinterpret_cast<ushort4*>(out)[i] = o;
  }
}

// ---------------- all 4 weights: fp32 [1024][1024] -> bf16 transpose (one kernel) ----
__global__ __launch_bounds__(256) void transp4(const float* __restrict__ wq,
                                               const float* __restrict__ wk,
                                               const float* __restrict__ wv,
                                               const float* __restrict__ wo,
                                               u16* __restrict__ wqkvt,
                                               u16* __restrict__ wot, float qscale) {
  __shared__ float tile[64][65];
  int z = blockIdx.z;
  const float* W = (z == 0) ? wq : (z == 1) ? wk : (z == 2) ? wv : wo;
  u16* out = (z < 3) ? (wqkvt + z * 1048576) : wot;
  float sc = (z == 0) ? qscale : 1.0f;
  int n0 = blockIdx.x * 64, k0 = blockIdx.y * 64;
  int t = threadIdx.x;
#pragma unroll
  for (int i = 0; i < 16; i++) {
    int idx = t + i * 256;
    int r = idx >> 6, c = idx & 63;
    tile[r][c] = W[(k0 + r) * 1024 + (n0 + c)];
  }
  __syncthreads();
#pragma unroll
  for (int i = 0; i < 16; i++) {
    int idx = t + i * 256;
    int r = idx >> 6, c = idx & 63;
    out[(n0 + r) * 1024 + (k0 + c)] = f2bf(tile[c][r] * sc);
  }
}

// ---------------- 2-phase GEMM, 64x128 tile (6 blocks/CU): C = A @ Bt^T -------------
// 4 waves, wave tile 32x64 (acc[2][4], 8 MFMA/step). LDS 24KB: A 2x(64x32), B 2x(128x32).
// Swizzle (R14-proven): phys 16B slot = g ^ ((row>>1)&3), pre-swizzled global source.
// MODE 0: fused QKV, LDS-bounce coalesced epilogue (Q/K rows; V transposed+key-perm).
// MODE 1: fp32 out [M][1024] = acc + bias[n]
template <int MODE>
__global__ __launch_bounds__(256, 6) void gemm2(const u16* __restrict__ A,
                                                const u16* __restrict__ Bt,
                                                const float* __restrict__ bias,
                                                void* __restrict__ outp) {
  constexpr int K = 1024, NT = K / 32;
  __shared__ __align__(16) u16 shm[12288];  // As: 0..4095 (2x2048), Bs: 4096..12287 (2x4096)
  int t = threadIdx.x, w = t >> 6, l = t & 63;
  int m0 = blockIdx.y * 64, n0 = blockIdx.x * 128;
  int wm = (w >> 1) * 32, wn = (w & 1) * 64;
  int g = l >> 4, ql = l & 15;
  int xs = (g ^ ((ql >> 1) & 3)) * 8;  // swizzled fragment chunk

  f32x4 acc[2][4];
#pragma unroll
  for (int i = 0; i < 2; i++)
#pragma unroll
    for (int j = 0; j < 4; j++) acc[i][j] = f32x4{0.f, 0.f, 0.f, 0.f};

  // staging: lane covers row (l>>2), phys chunk l&3; source col pre-swizzled
  int lrow = l >> 2, lcol = ((l & 3) ^ ((l >> 3) & 3)) * 8;
  const u16* Ag0 = A + (m0 + 16 * w + lrow) * K + lcol;   // wave w: A rows w*16..+16
  const u16* Bg0 = Bt + (n0 + 32 * w + lrow) * K + lcol;  // wave w: B rows w*32..+32
  u16* Asw[2] = {shm + 16 * w * 32, shm + 2048 + 16 * w * 32};
  u16* Bsw[2] = {shm + 4096 + 32 * w * 32, shm + 8192 + 32 * w * 32};

#define STAGE(buf, kt)                              \
  do {                                              \
    int k0_ = (kt) * 32;                            \
    gl_lds16(Ag0 + k0_, Asw[buf]);                  \
    gl_lds16(Bg0 + k0_, Bsw[buf]);                  \
    gl_lds16(Bg0 + 16 * K + k0_, Bsw[buf] + 512);   \
  } while (0)

#define COMPUTE(buf)                                                              \
  do {                                                                            \
    const u16* As_ = shm + (buf)*2048;                                            \
    const u16* Bs_ = shm + 4096 + (buf)*4096;                                     \
    s16x8 af[2], bv[4];                                                           \
    _Pragma("unroll") for (int fm = 0; fm < 2; fm++)                              \
        af[fm] = *reinterpret_cast<const s16x8*>(                                 \
            &As_[(wm + fm * 16 + ql) * 32 + xs]);                                 \
    _Pragma("unroll") for (int fn = 0; fn < 4; fn++)                              \
        bv[fn] = *reinterpret_cast<const s16x8*>(                                 \
            &Bs_[(wn + fn * 16 + ql) * 32 + xs]);                                 \
    _Pragma("unroll") for (int fm = 0; fm < 2; fm++)                              \
        _Pragma("unroll") for (int fn = 0; fn < 4; fn++)                          \
            acc[fm][fn] = MFMA16(af[fm], bv[fn], acc[fm][fn]);                    \
  } while (0)

  STAGE(0, 0);
  __syncthreads();
  int cur = 0;
  for (int kt = 0; kt < NT - 1; kt++) {
    STAGE(cur ^ 1, kt + 1);
    COMPUTE(cur);
    __syncthreads();
    cur ^= 1;
  }
  COMPUTE(cur);
#undef STAGE
#undef COMPUTE

  if (MODE == 1) {
#pragma unroll
    for (int fm = 0; fm < 2; fm++)
#pragma unroll
      for (int fn = 0; fn < 4; fn++)
#pragma unroll
        for (int j = 0; j < 4; j++) {
          int m = m0 + wm + fm * 16 + g * 4 + j;
          int n = n0 + wn + fn * 16 + ql;
          ((float*)outp)[m * 1024 + n] = acc[fm][fn][j] + bias[n];
        }
    return;
  }

  // MODE 0: LDS-bounce epilogue. Per-wave 16x68 tile overlaying the dead buffers.
  __syncthreads();
  u16* tlw = shm + w * 2048;
  int nb = n0 + wn;              // 64-aligned; whole wave band in one projection
  int proj = nb >> 10;
  int nn6 = (nb & 1023) >> 6;    // head-within-projection

  if (proj < 2) {
    u16* o = (u16*)outp + proj * 4194304;
#pragma unroll
    for (int fm = 0; fm < 2; fm++) {
#pragma unroll
      for (int fn = 0; fn < 4; fn++)
#pragma unroll
        for (int j = 0; j < 4; j++)
          tlw[(g * 4 + j) * 68 + fn * 16 + ql] = f2bf(acc[fm][fn][j]);
#pragma unroll
      for (int i = 0; i < 4; i++) {
        int row = i * 4 + g;
        u32x2 v = *reinterpret_cast<const u32x2*>(tlw + row * 68 + ql * 4);
        int m = m0 + wm + fm * 16 + row;
        int bh = (m >> 11) * 16 + nn6;
        *reinterpret_cast<u32x2*>(o + (bh * 2048 + (m & 2047)) * 64 + ql * 4) = v;
      }
    }
  } else {
    u16* o = (u16*)outp + 8388608;
    int kq = (l & 3) * 4;
    int pr = ((kq & 4) << 1) | ((kq & 8) >> 1);  // permuted base row (bits 2<->3)
#pragma unroll
    for (int fm = 0; fm < 2; fm++) {
#pragma unroll
      for (int fn = 0; fn < 4; fn++)
#pragma unroll
        for (int j = 0; j < 4; j++)
          tlw[(g * 4 + j) * 68 + fn * 16 + ql] = f2bf(acc[fm][fn][j]);
      int m = m0 + wm + fm * 16;
      int batch = m >> 11, key0 = m & 2047;
      int bh = batch * 16 + nn6;
#pragma unroll
      for (int i = 0; i < 4; i++) {
        int hd = i * 16 + (l >> 2);
        u16 v0 = tlw[(pr + 0) * 68 + hd];
        u16 v1 = tlw[(pr + 1) * 68 + hd];
        u16 v2 = tlw[(pr + 2) * 68 + hd];
        u16 v3 = tlw[(pr + 3) * 68 + hd];
        u32x2 v;
        v[0] = (u32)v0 | ((u32)v1 << 16);
        v[1] = (u32)v2 | ((u32)v3 << 16);
        *reinterpret_cast<u32x2*>(o + (bh * 64 + hd) * 2048 + key0 + kq) = v;
      }
    }
  }
}

// ---------------- flash attention: 8-wave blocks, shared K/V in LDS (R10) ----------
__global__ __launch_bounds__(512, 4) void attn_kernel(const u16* __restrict__ Q,
                                                      const u16* __restrict__ Kb,
                                                      const u16* __restrict__ Vt,
                                                      u16* __restrict__ Ctx,
                                                      u16* __restrict__ part_o,
                                                      float* __restrict__ part_l) {
  __shared__ __align__(16) u16 Kl[2][2048];
  __shared__ __align__(16) u16 Vl[2][2048];
  __shared__ __align__(16) u16 tl[8][32 * 68];
  int tid = threadIdx.x, w = tid >> 6, l = tid & 63;
  int lq = l & 31, h = l >> 5;

  int B = blockIdx.x;
  int head = (B & 7) + 8 * ((B >> 3) & 3);  // head % 8 == B % 8 -> XCD-pinned
  int u = B >> 5;                           // 0..15, longest chunks first
  const signed char QCv[16] = {3, 2, 4, 4, 6, 6, 6, 7, 7, 7, 7, 5, 5, 5, 1, 0};
  const signed char CKv[16] = {0, 0, 0, 1, 0, 1, 2, 0, 1, 2, 3, 0, 1, 2, 0, 0};
  int qc = QCv[u], ck = CKv[u];
  int t0, t1;
  if (qc == 4)      { t0 = ck * 20; t1 = t0 + 20; }
  else if (qc == 5) { t0 = ck * 16; t1 = t0 + 16; }
  else if (qc == 6) { t0 = (ck == 0) ? 0 : (ck == 1) ? 19 : 38;
                      t1 = (ck == 0) ? 19 : (ck == 1) ? 38 : 56; }
  else if (qc == 7) { t0 = ck * 16; t1 = t0 + 16; }
  else              { t0 = 0; t1 = (qc + 1) * 8; }
  int dtile = qc * 8 + w;
  int q0w = qc * 256 + w * 32;
  int q = q0w + lq;

  const u16* Qp = Q + (head * 2048 + q0w) * 64;
  const u16* Kp = Kb + head * 2048 * 64;
  const u16* Vp = Vt + head * 64 * 2048;

  s16x8 qf[4];
#pragma unroll
  for (int f = 0; f < 4; f++)
    qf[f] = *reinterpret_cast<const s16x8*>(Qp + lq * 64 + f * 16 + h * 8);

  const u16* gstage;
  int gstep, ldsoff;
  if (w < 4) {
    int row = w * 8 + (l >> 3);
    int c = (l & 7) ^ (row & 7);
    gstage = Kp + row * 64 + c * 8;
    gstep = 32 * 64;
    ldsoff = w * 512;
  } else {
    int lin = (w - 4) * 64 + l;
    int rp = lin >> 3, pos = lin & 7;
    int d = rp * 2 + (pos >> 2);
    int c = (pos & 3) ^ (rp & 3);
    gstage = Vp + d * 2048 + c * 8;
    gstep = 32;
    ldsoff = (w - 4) * 512;
  }

  f32x16 oacc[2];
#pragma unroll
  for (int dt = 0; dt < 2; dt++)
#pragma unroll
    for (int rr = 0; rr < 16; rr++) oacc[dt][rr] = 0.f;
  float lsum = 0.f;

#define STAGEKV(buf, kt)                                                  \
  gl_lds16(gstage + (kt) * gstep, ((w < 4) ? Kl[buf] : Vl[buf]) + ldsoff)

  STAGEKV(0, t0);
  __syncthreads();
  int cur = 0;

  for (int kt = t0; kt < t1; kt++) {
    if (kt + 1 < t1) STAGEKV(cur ^ 1, kt + 1);

    if (kt <= dtile) {
      s16x8 kc[4];
#pragma unroll
      for (int f = 0; f < 4; f++)
        kc[f] = *reinterpret_cast<const s16x8*>(
            &Kl[cur][lq * 64 + (((f * 2 + h) ^ (lq & 7)) * 8)]);

      f32x16 s;
#pragma unroll
      for (int rr = 0; rr < 16; rr++) s[rr] = 0.f;
      __builtin_amdgcn_s_setprio(1);
#pragma unroll
      for (int f = 0; f < 4; f++) s = MFMA32(kc[f], qf[f], s);
      __builtin_amdgcn_s_setprio(0);

      float p[16];
      if (kt == dtile) {
        int kb = kt * 32;
#pragma unroll
        for (int rr = 0; rr < 16; rr++) {
          int key = kb + (rr & 3) + 8 * (rr >> 2) + 4 * h;
          float e = exp2f(s[rr]);
          p[rr] = (key <= q) ? e : 0.f;
        }
      } else {
#pragma unroll
        for (int rr = 0; rr < 16; rr++) p[rr] = exp2f(s[rr]);
      }
#pragma unroll
      for (int rr = 0; rr < 16; rr++) lsum += p[rr];

      u32 pw[2][4];
#pragma unroll
      for (int kh = 0; kh < 2; kh++)
#pragma unroll
        for (int uu = 0; uu < 4; uu++)
          pw[kh][uu] = cvtpk(p[kh * 8 + 2 * uu], p[kh * 8 + 2 * uu + 1]);

      s16x8 vf[2][2];
#pragma unroll
      for (int dt = 0; dt < 2; dt++)
#pragma unroll
        for (int kh = 0; kh < 2; kh++) {
          int rp = dt * 16 + (lq >> 1);
          int soff = rp * 64 + (lq & 1) * 32 + (((kh * 2 + h) ^ (rp & 3)) * 8);
          vf[dt][kh] = *reinterpret_cast<const s16x8*>(&Vl[cur][soff]);
        }

      __builtin_amdgcn_s_setprio(1);
#pragma unroll
      for (int kh = 0; kh < 2; kh++) {
        s16x8 pf = __builtin_bit_cast(
            s16x8, u32x4{pw[kh][0], pw[kh][1], pw[kh][2], pw[kh][3]});
        oacc[0] = MFMA32(vf[0][kh], pf, oacc[0]);
        oacc[1] = MFMA32(vf[1][kh], pf, oacc[1]);
      }
      __builtin_amdgcn_s_setprio(0);
    }

    __syncthreads();
    cur ^= 1;
  }
#undef STAGEKV

  if (qc >= 4) {
    int base = (qc == 4) ? 0 : (qc == 5) ? 2 : (qc == 6) ? 5 : 8;
    int rec = head * 12 + base + ck;
    u32* po = reinterpret_cast<u32*>(part_o) + (size_t)rec * 8192 + w * 1024 + l * 16;
#pragma unroll
    for (int dt = 0; dt < 2; dt++)
#pragma unroll
      for (int i = 0; i < 8; i++)
        po[dt * 8 + i] = pack2bf(oacc[dt][2 * i], oacc[dt][2 * i + 1]);
    part_l[(size_t)rec * 512 + w * 64 + l] = lsum;
    return;
  }

  float ltot = lsum + __shfl_xor(lsum, 32);
  float invl = 1.0f / ltot;
  u16* myl = tl[w];
#pragma unroll
  for (int dt = 0; dt < 2; dt++)
#pragma unroll
    for (int i = 0; i < 8; i++) {
      int d = ((2 * i) & 3) + 8 * (i >> 1) + 4 * h + dt * 32;
      u32 pkv = pack2bf(oacc[dt][2 * i] * invl, oacc[dt][2 * i + 1] * invl);
      *reinterpret_cast<u32*>(myl + lq * 68 + d) = pkv;
    }

  int b = head >> 4, hh = head & 15;
  int gbase = b * 2048 + q0w;
#pragma unroll
  for (int i = 0; i < 8; i++) {
    int chunkk = i * 64 + l;
    int row = chunkk >> 4, col4 = (chunkk & 15) * 4;
    u32x2 v = *reinterpret_cast<const u32x2*>(myl + row * 68 + col4);
    *reinterpret_cast<u32x2*>(Ctx + (gbase + row) * 1024 + hh * 64 + col4) = v;
  }
}

// ---------------- combine 2-4 partials per (head, qc>=4, wave q-tile) -> Ctx --------
__global__ __launch_bounds__(256) void attn_combine(const u16* __restrict__ part_o,
                                                    const float* __restrict__ part_l,
                                                    u16* __restrict__ Ctx) {
  __shared__ __align__(16) u16 tl[4][32 * 68];
  int wv = threadIdx.x >> 6, l = threadIdx.x & 63;
  int lq = l & 31, h = l >> 5;
  int unit = blockIdx.x * 4 + wv;
  int head = unit & 31, rest = unit >> 5;
  int qc = 4 + (rest >> 3), w = rest & 7;
  int nc = (qc == 4) ? 2 : (qc == 7) ? 4 : 3;
  int base = (qc == 4) ? 0 : (qc == 5) ? 2 : (qc == 6) ? 5 : 8;
  int rec0 = head * 12 + base;

  float lsum = 0.f;
  float of[32];
#pragma unroll
  for (int i = 0; i < 32; i++) of[i] = 0.f;
  for (int cc = 0; cc < nc; cc++) {
    int rec = rec0 + cc;
    lsum += part_l[(size_t)rec * 512 + w * 64 + l];
    const u32* po =
        reinterpret_cast<const u32*>(part_o) + (size_t)rec * 8192 + w * 1024 + l * 16;
#pragma unroll
    for (int uu = 0; uu < 16; uu++) {
      u32 a = po[uu];
      of[2 * uu] += bf2f(a & 0xFFFFu);
      of[2 * uu + 1] += bf2f(a >> 16);
    }
  }

  float ltot = lsum + __shfl_xor(lsum, 32);
  float invl = 1.0f / ltot;

  u16* myl = tl[wv];
#pragma unroll
  for (int dt = 0; dt < 2; dt++)
#pragma unroll
    for (int i = 0; i < 8; i++) {
      int uu = dt * 8 + i;
      int d = ((2 * i) & 3) + 8 * (i >> 1) + 4 * h + dt * 32;
      *reinterpret_cast<u32*>(myl + lq * 68 + d) =
          pack2bf(of[2 * uu] * invl, of[2 * uu + 1] * invl);
    }

  int b_ = head >> 4, hh = head & 15;
  int gbase = b_ * 2048 + qc * 256 + w * 32;
#pragma unroll
  for (int i = 0; i < 8; i++) {
    int chunkk = i * 64 + l;
    int row = chunkk >> 4, col4 = (chunkk & 15) * 4;
    u32x2 v = *reinterpret_cast<const u32x2*>(myl + row * 68 + col4);
    *reinterpret_cast<u32x2*>(Ctx + (gbase + row) * 1024 + hh * 64 + col4) = v;
  }
}

extern "C" void kernel_launch(void* const* d_in, const int* in_sizes, int n_in,
                              void* d_out, int out_size, void* d_ws, size_t ws_size,
                              hipStream_t stream) {
  const float* x = (const float*)d_in[0];
  const float* wq = (const float*)d_in[1];
  const float* wk = (const float*)d_in[2];
  const float* wv = (const float*)d_in[3];
  const float* wo = (const float*)d_in[4];
  const float* bo = (const float*)d_in[5];

  char* ws = (char*)d_ws;
  const size_t MB = 1 << 20;
  u16* xb    = (u16*)(ws + 0 * MB);    // 8 MB : x bf16 (dead after QKV GEMM)
  u16* wqkvt = (u16*)(ws + 8 * MB);    // 6 MB : [wq^T;wk^T;wv^T] (dead after QKV GEMM)
  u16* wot   = (u16*)(ws + 14 * MB);   // 2 MB : wo^T (live until final GEMM)
  u16* qkv   = (u16*)(ws + 16 * MB);   // 24 MB: Q @16, K @24, V^T @32
  u16* ctx   = (u16*)(ws + 40 * MB);   // 8 MB : ctx [4096][1024]
  // attention partials alias the dead xb/wqkvt region (13.4 MB < 14 MB):
  u16* part_o   = (u16*)(ws + 0 * MB);        // 12 MB : 384 records x 32 KB
  float* part_l = (float*)(ws + 12582912);    // 0.75 MB: 384 records x 512 floats

  const float QSCALE = 0.125f * 1.44269504f;  // 1/sqrt(64) * log2(e)

  cvt_bf16<<<4096, 256, 0, stream>>>(x, xb, 1048576);
  transp4<<<dim3(16, 16, 4), 256, 0, stream>>>(wq, wk, wv, wo, wqkvt, wot, QSCALE);

  gemm2<0><<<dim3(24, 64), 256, 0, stream>>>(xb, wqkvt, nullptr, qkv);

  attn_kernel<<<512, 512, 0, stream>>>(qkv, qkv + 4194304, qkv + 8388608, ctx,
                                       part_o, part_l);
  attn_combine<<<256, 256, 0, stream>>>(part_o, part_l, ctx);

  gemm2<1><<<dim3(8, 64), 256, 0, stream>>>(ctx, wot, bo, d_out);
}

// Round 16
// 114.987 us; speedup vs baseline: 1.1397x; 1.0229x over previous
//
#include <hip/hip_runtime.h>

typedef short s16x8 __attribute__((ext_vector_type(8)));
typedef float f32x4 __attribute__((ext_vector_type(4)));
typedef float f32x16 __attribute__((ext_vector_type(16)));
typedef unsigned int u32;
typedef u32 u32x2 __attribute__((ext_vector_type(2)));
typedef u32 u32x4 __attribute__((ext_vector_type(4)));
typedef unsigned short u16;

#define MFMA16(a, b, c) __builtin_amdgcn_mfma_f32_16x16x32_bf16((a), (b), (c), 0, 0, 0)
#define MFMA32(a, b, c) __builtin_amdgcn_mfma_f32_32x32x16_bf16((a), (b), (c), 0, 0, 0)

__device__ __forceinline__ u16 f2bf(float f) {
  unsigned u = __builtin_bit_cast(unsigned, f);
  unsigned r = (u + 0x7FFFu + ((u >> 16) & 1u)) >> 16;
  return (u16)r;
}

__device__ __forceinline__ u32 pack2bf(float lo, float hi) {
  return (u32)f2bf(lo) | ((u32)f2bf(hi) << 16);
}

__device__ __forceinline__ u32 cvtpk(float lo, float hi) {
  u32 r;
  asm("v_cvt_pk_bf16_f32 %0, %1, %2" : "=v"(r) : "v"(lo), "v"(hi));
  return r;
}

__device__ __forceinline__ float bf2f(u32 lo16) {
  return __builtin_bit_cast(float, lo16 << 16);
}

// async global->LDS, 16B per lane. LDS dest must be wave-uniform base (HW adds lane*16).
__device__ __forceinline__ void gl_lds16(const u16* g, u16* s) {
  __builtin_amdgcn_global_load_lds(
      (const __attribute__((address_space(1))) void*)g,
      (__attribute__((address_space(3))) void*)s, 16, 0, 0);
}

// ---------------- merged prepass: x->bf16 (blocks 0-4095) + 4 weight transposes ----
__global__ __launch_bounds__(256) void prep(const float* __restrict__ x,
                                            u16* __restrict__ xb,
                                            const float* __restrict__ wq,
                                            const float* __restrict__ wk,
                                            const float* __restrict__ wv,
                                            const float* __restrict__ wo,
                                            u16* __restrict__ wqkvt,
                                            u16* __restrict__ wot, float qscale) {
  __shared__ float tile[64][65];
  int B = blockIdx.x, t = threadIdx.x;
  if (B < 4096) {
    int i = B * 256 + t;
    float4 v = reinterpret_cast<const float4*>(x)[i];
    ushort4 o;
    o.x = f2bf(v.x); o.y = f2bf(v.y); o.z = f2bf(v.z); o.w = f2bf(v.w);
    reinterpret_cast<ushort4*>(xb)[i] = o;
    return;
  }
  int zz = (B - 4096) >> 8, bb = (B - 4096) & 255;
  const float* W = (zz == 0) ? wq : (zz == 1) ? wk : (zz == 2) ? wv : wo;
  u16* out = (zz < 3) ? (wqkvt + zz * 1048576) : wot;
  float sc = (zz == 0) ? qscale : 1.0f;
  int n0 = (bb & 15) * 64, k0 = (bb >> 4) * 64;
#pragma unroll
  for (int i = 0; i < 16; i++) {
    int idx = t + i * 256;
    int r = idx >> 6, c = idx & 63;
    tile[r][c] = W[(k0 + r) * 1024 + (n0 + c)];
  }
  __syncthreads();
#pragma unroll
  for (int i = 0; i < 16; i++) {
    int idx = t + i * 256;
    int r = idx >> 6, c = idx & 63;
    out[(n0 + r) * 1024 + (k0 + c)] = f2bf(tile[c][r] * sc);
  }
}

// ---------------- 2-phase GEMM, 64x128 tile (6 blocks/CU): C = A @ Bt^T -------------
// (R15-proven) 4 waves, wave tile 32x64. Swizzle: phys slot = g ^ ((row>>1)&3).
// MODE 0: fused QKV, LDS-bounce coalesced epilogue. MODE 1: fp32 + bias.
template <int MODE>
__global__ __launch_bounds__(256, 6) void gemm2(const u16* __restrict__ A,
                                                const u16* __restrict__ Bt,
                                                const float* __restrict__ bias,
                                                void* __restrict__ outp) {
  constexpr int K = 1024, NT = K / 32;
  __shared__ __align__(16) u16 shm[12288];
  int t = threadIdx.x, w = t >> 6, l = t & 63;
  int m0 = blockIdx.y * 64, n0 = blockIdx.x * 128;
  int wm = (w >> 1) * 32, wn = (w & 1) * 64;
  int g = l >> 4, ql = l & 15;
  int xs = (g ^ ((ql >> 1) & 3)) * 8;

  f32x4 acc[2][4];
#pragma unroll
  for (int i = 0; i < 2; i++)
#pragma unroll
    for (int j = 0; j < 4; j++) acc[i][j] = f32x4{0.f, 0.f, 0.f, 0.f};

  int lrow = l >> 2, lcol = ((l & 3) ^ ((l >> 3) & 3)) * 8;
  const u16* Ag0 = A + (m0 + 16 * w + lrow) * K + lcol;
  const u16* Bg0 = Bt + (n0 + 32 * w + lrow) * K + lcol;
  u16* Asw[2] = {shm + 16 * w * 32, shm + 2048 + 16 * w * 32};
  u16* Bsw[2] = {shm + 4096 + 32 * w * 32, shm + 8192 + 32 * w * 32};

#define STAGE(buf, kt)                              \
  do {                                              \
    int k0_ = (kt) * 32;                            \
    gl_lds16(Ag0 + k0_, Asw[buf]);                  \
    gl_lds16(Bg0 + k0_, Bsw[buf]);                  \
    gl_lds16(Bg0 + 16 * K + k0_, Bsw[buf] + 512);   \
  } while (0)

#define COMPUTE(buf)                                                              \
  do {                                                                            \
    const u16* As_ = shm + (buf)*2048;                                            \
    const u16* Bs_ = shm + 4096 + (buf)*4096;                                     \
    s16x8 af[2], bv[4];                                                           \
    _Pragma("unroll") for (int fm = 0; fm < 2; fm++)                              \
        af[fm] = *reinterpret_cast<const s16x8*>(                                 \
            &As_[(wm + fm * 16 + ql) * 32 + xs]);                                 \
    _Pragma("unroll") for (int fn = 0; fn < 4; fn++)                              \
        bv[fn] = *reinterpret_cast<const s16x8*>(                                 \
            &Bs_[(wn + fn * 16 + ql) * 32 + xs]);                                 \
    _Pragma("unroll") for (int fm = 0; fm < 2; fm++)                              \
        _Pragma("unroll") for (int fn = 0; fn < 4; fn++)                          \
            acc[fm][fn] = MFMA16(af[fm], bv[fn], acc[fm][fn]);                    \
  } while (0)

  STAGE(0, 0);
  __syncthreads();
  int cur = 0;
  for (int kt = 0; kt < NT - 1; kt++) {
    STAGE(cur ^ 1, kt + 1);
    COMPUTE(cur);
    __syncthreads();
    cur ^= 1;
  }
  COMPUTE(cur);
#undef STAGE
#undef COMPUTE

  if (MODE == 1) {
#pragma unroll
    for (int fm = 0; fm < 2; fm++)
#pragma unroll
      for (int fn = 0; fn < 4; fn++)
#pragma unroll
        for (int j = 0; j < 4; j++) {
          int m = m0 + wm + fm * 16 + g * 4 + j;
          int n = n0 + wn + fn * 16 + ql;
          ((float*)outp)[m * 1024 + n] = acc[fm][fn][j] + bias[n];
        }
    return;
  }

  __syncthreads();
  u16* tlw = shm + w * 2048;
  int nb = n0 + wn;
  int proj = nb >> 10;
  int nn6 = (nb & 1023) >> 6;

  if (proj < 2) {
    u16* o = (u16*)outp + proj * 4194304;
#pragma unroll
    for (int fm = 0; fm < 2; fm++) {
#pragma unroll
      for (int fn = 0; fn < 4; fn++)
#pragma unroll
        for (int j = 0; j < 4; j++)
          tlw[(g * 4 + j) * 68 + fn * 16 + ql] = f2bf(acc[fm][fn][j]);
#pragma unroll
      for (int i = 0; i < 4; i++) {
        int row = i * 4 + g;
        u32x2 v = *reinterpret_cast<const u32x2*>(tlw + row * 68 + ql * 4);
        int m = m0 + wm + fm * 16 + row;
        int bh = (m >> 11) * 16 + nn6;
        *reinterpret_cast<u32x2*>(o + (bh * 2048 + (m & 2047)) * 64 + ql * 4) = v;
      }
    }
  } else {
    u16* o = (u16*)outp + 8388608;
    int kq = (l & 3) * 4;
    int pr = ((kq & 4) << 1) | ((kq & 8) >> 1);
#pragma unroll
    for (int fm = 0; fm < 2; fm++) {
#pragma unroll
      for (int fn = 0; fn < 4; fn++)
#pragma unroll
        for (int j = 0; j < 4; j++)
          tlw[(g * 4 + j) * 68 + fn * 16 + ql] = f2bf(acc[fm][fn][j]);
      int m = m0 + wm + fm * 16;
      int batch = m >> 11, key0 = m & 2047;
      int bh = batch * 16 + nn6;
#pragma unroll
      for (int i = 0; i < 4; i++) {
        int hd = i * 16 + (l >> 2);
        u16 v0 = tlw[(pr + 0) * 68 + hd];
        u16 v1 = tlw[(pr + 1) * 68 + hd];
        u16 v2 = tlw[(pr + 2) * 68 + hd];
        u16 v3 = tlw[(pr + 3) * 68 + hd];
        u32x2 v;
        v[0] = (u32)v0 | ((u32)v1 << 16);
        v[1] = (u32)v2 | ((u32)v3 << 16);
        *reinterpret_cast<u32x2*>(o + (bh * 64 + hd) * 2048 + key0 + kq) = v;
      }
    }
  }
}

// ---------------- flash attention: 8-wave blocks, 4-tile LDS windows ---------------
// Q,K: [BH=32][S=2048][64] bf16 (Q pre-scaled); Vt: [BH][64][2048] bf16 (key-permuted).
// 512 blocks x 512 threads. Per window (4 x 32-key tiles, 32KB): stage NEXT window
// first (into the buf whose compute finished last iteration - barrier-protected),
// compute 4 tiles, ONE __syncthreads. Chunking in window units; partial layout = R10.
__global__ __launch_bounds__(512, 4) void attn_kernel(const u16* __restrict__ Q,
                                                      const u16* __restrict__ Kb,
                                                      const u16* __restrict__ Vt,
                                                      u16* __restrict__ Ctx,
                                                      u16* __restrict__ part_o,
                                                      float* __restrict__ part_l) {
  // buf b at shm + b*16384: K tiles j*2048, V tiles 8192 + j*2048. tl overlays shm.
  __shared__ __align__(16) u16 shm[32768];
  int tid = threadIdx.x, w = tid >> 6, l = tid & 63;
  int lq = l & 31, h = l >> 5;

  int B = blockIdx.x;
  int head = (B & 7) + 8 * ((B >> 3) & 3);  // head % 8 == B % 8 -> XCD-pinned
  int u = B >> 5;                           // 0..15, longest first
  const signed char QCv[16] = {3, 2, 4, 4, 6, 6, 6, 7, 7, 7, 7, 5, 5, 5, 1, 0};
  const signed char T0W[16] = {0, 0, 0, 5, 0, 5, 10, 0, 4, 8, 12, 0, 4, 8, 0, 0};
  const signed char NWv[16] = {8, 6, 5, 5, 5, 5, 4, 4, 4, 4, 4, 4, 4, 4, 4, 2};
  const signed char CKv[16] = {0, 0, 0, 1, 0, 1, 2, 0, 1, 2, 3, 0, 1, 2, 0, 0};
  int qc = QCv[u], ck = CKv[u], t0w = T0W[u], nw = NWv[u];
  int dtile = qc * 8 + w;
  int q0w = qc * 256 + w * 32;
  int q = q0w + lq;

  const u16* Qp = Q + (head * 2048 + q0w) * 64;
  const u16* Kp = Kb + head * 2048 * 64;
  const u16* Vp = Vt + head * 64 * 2048;

  s16x8 qf[4];
#pragma unroll
  for (int f = 0; f < 4; f++)
    qf[f] = *reinterpret_cast<const s16x8*>(Qp + lq * 64 + f * 16 + h * 8);

  // staging source (pre-swizzled global, R10-proven) + per-wave LDS offset
  const u16* gstage;
  int gstep, ldsoff;
  if (w < 4) {
    int row = w * 8 + (l >> 3);
    int c = (l & 7) ^ (row & 7);
    gstage = Kp + row * 64 + c * 8;
    gstep = 32 * 64;
    ldsoff = w * 512;  // within K tile slot
  } else {
    int lin = (w - 4) * 64 + l;
    int rp = lin >> 3, pos = lin & 7;
    int d = rp * 2 + (pos >> 2);
    int c = (pos & 3) ^ (rp & 3);
    gstage = Vp + d * 2048 + c * 8;
    gstep = 32;
    ldsoff = 8192 + (w - 4) * 512;  // within V tile slot
  }

  f32x16 oacc[2];
#pragma unroll
  for (int dt = 0; dt < 2; dt++)
#pragma unroll
    for (int rr = 0; rr < 16; rr++) oacc[dt][rr] = 0.f;
  float lsum = 0.f;

  // stage window aw (4 tiles) into buf
#define STAGEW(buf, aw)                                                      \
  do {                                                                       \
    u16* sb_ = shm + (buf)*16384 + ldsoff;                                   \
    _Pragma("unroll") for (int j_ = 0; j_ < 4; j_++)                         \
        gl_lds16(gstage + ((aw)*4 + j_) * gstep, sb_ + j_ * 2048);           \
  } while (0)

  STAGEW(0, t0w);
  __syncthreads();
  int cur = 0;

  for (int wi = 0; wi < nw; wi++) {
    if (wi + 1 < nw) STAGEW(cur ^ 1, t0w + wi + 1);

    const u16* kwin = shm + cur * 16384;
    const u16* vwin = kwin + 8192;
#pragma unroll
    for (int j = 0; j < 4; j++) {
      int kt = (t0w + wi) * 4 + j;
      if (kt <= dtile) {
        const u16* ktile = kwin + j * 2048;
        s16x8 kc[4];
#pragma unroll
        for (int f = 0; f < 4; f++)
          kc[f] = *reinterpret_cast<const s16x8*>(
              &ktile[lq * 64 + (((f * 2 + h) ^ (lq & 7)) * 8)]);

        f32x16 s;
#pragma unroll
        for (int rr = 0; rr < 16; rr++) s[rr] = 0.f;
        __builtin_amdgcn_s_setprio(1);
#pragma unroll
        for (int f = 0; f < 4; f++) s = MFMA32(kc[f], qf[f], s);
        __builtin_amdgcn_s_setprio(0);

        float p[16];
        if (kt == dtile) {
          int kb = kt * 32;
#pragma unroll
          for (int rr = 0; rr < 16; rr++) {
            int key = kb + (rr & 3) + 8 * (rr >> 2) + 4 * h;
            float e = exp2f(s[rr]);
            p[rr] = (key <= q) ? e : 0.f;
          }
        } else {
#pragma unroll
          for (int rr = 0; rr < 16; rr++) p[rr] = exp2f(s[rr]);
        }
#pragma unroll
        for (int rr = 0; rr < 16; rr++) lsum += p[rr];

        u32 pw[2][4];
#pragma unroll
        for (int kh = 0; kh < 2; kh++)
#pragma unroll
          for (int uu = 0; uu < 4; uu++)
            pw[kh][uu] = cvtpk(p[kh * 8 + 2 * uu], p[kh * 8 + 2 * uu + 1]);

        const u16* vtile = vwin + j * 2048;
        s16x8 vf[2][2];
#pragma unroll
        for (int dt = 0; dt < 2; dt++)
#pragma unroll
          for (int kh = 0; kh < 2; kh++) {
            int rp = dt * 16 + (lq >> 1);
            int soff = rp * 64 + (lq & 1) * 32 + (((kh * 2 + h) ^ (rp & 3)) * 8);
            vf[dt][kh] = *reinterpret_cast<const s16x8*>(&vtile[soff]);
          }

        __builtin_amdgcn_s_setprio(1);
#pragma unroll
        for (int kh = 0; kh < 2; kh++) {
          s16x8 pf = __builtin_bit_cast(
              s16x8, u32x4{pw[kh][0], pw[kh][1], pw[kh][2], pw[kh][3]});
          oacc[0] = MFMA32(vf[0][kh], pf, oacc[0]);
          oacc[1] = MFMA32(vf[1][kh], pf, oacc[1]);
        }
        __builtin_amdgcn_s_setprio(0);
      }
    }

    __syncthreads();
    cur ^= 1;
  }
#undef STAGEW

  if (qc >= 4) {
    // partial record layout identical to R10
    int base = (qc == 4) ? 0 : (qc == 5) ? 2 : (qc == 6) ? 5 : 8;
    int rec = head * 12 + base + ck;
    u32* po = reinterpret_cast<u32*>(part_o) + (size_t)rec * 8192 + w * 1024 + l * 16;
#pragma unroll
    for (int dt = 0; dt < 2; dt++)
#pragma unroll
      for (int i = 0; i < 8; i++)
        po[dt * 8 + i] = pack2bf(oacc[dt][2 * i], oacc[dt][2 * i + 1]);
    part_l[(size_t)rec * 512 + w * 64 + l] = lsum;
    return;
  }

  // direct path: normalize, transpose O^T through LDS (overlay, post-barrier), store
  float ltot = lsum + __shfl_xor(lsum, 32);
  float invl = 1.0f / ltot;
  u16* myl = shm + w * 2176;
#pragma unroll
  for (int dt = 0; dt < 2; dt++)
#pragma unroll
    for (int i = 0; i < 8; i++) {
      int d = ((2 * i) & 3) + 8 * (i >> 1) + 4 * h + dt * 32;
      u32 pkv = pack2bf(oacc[dt][2 * i] * invl, oacc[dt][2 * i + 1] * invl);
      *reinterpret_cast<u32*>(myl + lq * 68 + d) = pkv;
    }

  int b = head >> 4, hh = head & 15;
  int gbase = b * 2048 + q0w;
#pragma unroll
  for (int i = 0; i < 8; i++) {
    int chunkk = i * 64 + l;
    int row = chunkk >> 4, col4 = (chunkk & 15) * 4;
    u32x2 v = *reinterpret_cast<const u32x2*>(myl + row * 68 + col4);
    *reinterpret_cast<u32x2*>(Ctx + (gbase + row) * 1024 + hh * 64 + col4) = v;
  }
}

// ---------------- combine 2-4 partials per (head, qc>=4, wave q-tile) -> Ctx --------
__global__ __launch_bounds__(256) void attn_combine(const u16* __restrict__ part_o,
                                                    const float* __restrict__ part_l,
                                                    u16* __restrict__ Ctx) {
  __shared__ __align__(16) u16 tl[4][32 * 68];
  int wv = threadIdx.x >> 6, l = threadIdx.x & 63;
  int lq = l & 31, h = l >> 5;
  int unit = blockIdx.x * 4 + wv;
  int head = unit & 31, rest = unit >> 5;
  int qc = 4 + (rest >> 3), w = rest & 7;
  int nc = (qc == 4) ? 2 : (qc == 7) ? 4 : 3;
  int base = (qc == 4) ? 0 : (qc == 5) ? 2 : (qc == 6) ? 5 : 8;
  int rec0 = head * 12 + base;

  float lsum = 0.f;
  float of[32];
#pragma unroll
  for (int i = 0; i < 32; i++) of[i] = 0.f;
  for (int cc = 0; cc < nc; cc++) {
    int rec = rec0 + cc;
    lsum += part_l[(size_t)rec * 512 + w * 64 + l];
    const u32* po =
        reinterpret_cast<const u32*>(part_o) + (size_t)rec * 8192 + w * 1024 + l * 16;
#pragma unroll
    for (int uu = 0; uu < 16; uu++) {
      u32 a = po[uu];
      of[2 * uu] += bf2f(a & 0xFFFFu);
      of[2 * uu + 1] += bf2f(a >> 16);
    }
  }

  float ltot = lsum + __shfl_xor(lsum, 32);
  float invl = 1.0f / ltot;

  u16* myl = tl[wv];
#pragma unroll
  for (int dt = 0; dt < 2; dt++)
#pragma unroll
    for (int i = 0; i < 8; i++) {
      int uu = dt * 8 + i;
      int d = ((2 * i) & 3) + 8 * (i >> 1) + 4 * h + dt * 32;
      *reinterpret_cast<u32*>(myl + lq * 68 + d) =
          pack2bf(of[2 * uu] * invl, of[2 * uu + 1] * invl);
    }

  int b_ = head >> 4, hh = head & 15;
  int gbase = b_ * 2048 + qc * 256 + w * 32;
#pragma unroll
  for (int i = 0; i < 8; i++) {
    int chunkk = i * 64 + l;
    int row = chunkk >> 4, col4 = (chunkk & 15) * 4;
    u32x2 v = *reinterpret_cast<const u32x2*>(myl + row * 68 + col4);
    *reinterpret_cast<u32x2*>(Ctx + (gbase + row) * 1024 + hh * 64 + col4) = v;
  }
}

extern "C" void kernel_launch(void* const* d_in, const int* in_sizes, int n_in,
                              void* d_out, int out_size, void* d_ws, size_t ws_size,
                              hipStream_t stream) {
  const float* x = (const float*)d_in[0];
  const float* wq = (const float*)d_in[1];
  const float* wk = (const float*)d_in[2];
  const float* wv = (const float*)d_in[3];
  const float* wo = (const float*)d_in[4];
  const float* bo = (const float*)d_in[5];

  char* ws = (char*)d_ws;
  const size_t MB = 1 << 20;
  u16* xb    = (u16*)(ws + 0 * MB);    // 8 MB : x bf16 (dead after QKV GEMM)
  u16* wqkvt = (u16*)(ws + 8 * MB);    // 6 MB : [wq^T;wk^T;wv^T] (dead after QKV GEMM)
  u16* wot   = (u16*)(ws + 14 * MB);   // 2 MB : wo^T (live until final GEMM)
  u16* qkv   = (u16*)(ws + 16 * MB);   // 24 MB: Q @16, K @24, V^T @32
  u16* ctx   = (u16*)(ws + 40 * MB);   // 8 MB : ctx [4096][1024]
  // attention partials alias the dead xb/wqkvt region (13.4 MB < 14 MB):
  u16* part_o   = (u16*)(ws + 0 * MB);        // 12 MB : 384 records x 32 KB
  float* part_l = (float*)(ws + 12582912);    // 0.75 MB: 384 records x 512 floats

  const float QSCALE = 0.125f * 1.44269504f;  // 1/sqrt(64) * log2(e)

  prep<<<5120, 256, 0, stream>>>(x, xb, wq, wk, wv, wo, wqkvt, wot, QSCALE);

  gemm2<0><<<dim3(24, 64), 256, 0, stream>>>(xb, wqkvt, nullptr, qkv);

  attn_kernel<<<512, 512, 0, stream>>>(qkv, qkv + 4194304, qkv + 8388608, ctx,
                                       part_o, part_l);
  attn_combine<<<256, 256, 0, stream>>>(part_o, part_l, ctx);

  gemm2<1><<<dim3(8, 64), 256, 0, stream>>>(ctx, wot, bo, d_out);
}